// Round 14
// baseline (414.477 us; speedup 1.0000x reference)
//
#include <hip/hip_runtime.h>
#include <stdint.h>

typedef float f32x4 __attribute__((ext_vector_type(4)));
typedef short s16x8 __attribute__((ext_vector_type(8)));
typedef short s16x4 __attribute__((ext_vector_type(4)));
typedef unsigned int u32x4 __attribute__((ext_vector_type(4)));

#define M_TOTAL 8192
#define DM 1024
#define HID 4096
#define SEQ 1024
#define NH 16
#define DH 64

#define BAR() __builtin_amdgcn_s_barrier()
#define VMCNT8() do { asm volatile("s_waitcnt vmcnt(8)" ::: "memory"); __builtin_amdgcn_sched_barrier(0); } while (0)
#define VMCNT0() do { asm volatile("s_waitcnt vmcnt(0)" ::: "memory"); __builtin_amdgcn_sched_barrier(0); } while (0)
#define MFMA16 __builtin_amdgcn_mfma_f32_16x16x32_bf16

__device__ __forceinline__ unsigned short f2bf(float f) {
  unsigned int u = __float_as_uint(f);
  u = (u + 0x7fffu + ((u >> 16) & 1u)) >> 16;
  return (unsigned short)u;
}

// packed f32x2 -> bf16x2 in one instruction (gfx950)
__device__ __forceinline__ unsigned int cvt_pk_bf16(float lo, float hi) {
  unsigned int r;
  asm("v_cvt_pk_bf16_f32 %0, %1, %2" : "=v"(r) : "v"(lo), "v"(hi));
  return r;
}

// raw v_exp_f32: D = 2^S0
__device__ __forceinline__ float exp2_fast(float x) {
  float r;
  asm("v_exp_f32 %0, %1" : "=v"(r) : "v"(x));
  return r;
}

__device__ __forceinline__ void gload16(const void* g, void* l) {
  __builtin_amdgcn_global_load_lds((__attribute__((address_space(1))) void*)g,
                                   (__attribute__((address_space(3))) void*)l,
                                   16, 0, 0);
}

// fast erf (Abramowitz-Stegun 7.1.26, |err| <= 1.5e-7)
__device__ __forceinline__ float erf_fast(float z) {
  const float az = fabsf(z);
  const float tt = 1.0f / fmaf(0.3275911f, az, 1.0f);
  float poly = fmaf(1.061405429f, tt, -1.453152027f);
  poly = fmaf(poly, tt, 1.421413741f);
  poly = fmaf(poly, tt, -0.284496736f);
  poly = fmaf(poly, tt, 0.254829592f);
  poly *= tt;
  const float e = __expf(-az * az);
  const float r = 1.0f - poly * e;
  return (z < 0.f) ? -r : r;
}

// ------- batched transpose+cast f32 -> bf16 for all 6 weight matrices -------
__global__ void tcast_all(const float* __restrict__ wq, const float* __restrict__ wk,
                          const float* __restrict__ wv, const float* __restrict__ wo,
                          const float* __restrict__ w1, const float* __restrict__ w2,
                          unsigned short* __restrict__ WTqkv, unsigned short* __restrict__ WTo,
                          unsigned short* __restrict__ WT1, unsigned short* __restrict__ WT2) {
  __shared__ float tile[32][33];
  const int b = blockIdx.x;
  const float* W;
  unsigned short* WT;
  int K, N, bn, bk;
  if (b < 4096) {
    const int j = b >> 10, t2 = b & 1023;
    K = 1024; N = 1024;
    bn = t2 & 31; bk = t2 >> 5;
    W = (j == 0) ? wq : (j == 1) ? wk : (j == 2) ? wv : wo;
    WT = (j < 3) ? (WTqkv + (size_t)j * 1024 * 1024) : WTo;
  } else if (b < 8192) {
    const int t2 = b - 4096;
    K = 1024; N = 4096;
    bn = t2 & 127; bk = t2 >> 7;
    W = w1; WT = WT1;
  } else {
    const int t2 = b - 8192;
    K = 4096; N = 1024;
    bn = t2 & 31; bk = t2 >> 5;
    W = w2; WT = WT2;
  }
  const int tx = threadIdx.x, ty = threadIdx.y;  // 32 x 8
#pragma unroll
  for (int i = 0; i < 32; i += 8)
    tile[ty + i][tx] = W[(size_t)(bk * 32 + ty + i) * N + bn * 32 + tx];
  __syncthreads();
#pragma unroll
  for (int i = 0; i < 32; i += 8)
    WT[(size_t)(bn * 32 + ty + i) * K + bk * 32 + tx] = f2bf(tile[tx][ty + i]);
}

// ---------------- LayerNorm (ddof=1) f32 in -> bf16 out ---------------------
__global__ __launch_bounds__(256)
void ln_kernel(const float* __restrict__ x, const float* __restrict__ alpha,
               const float* __restrict__ beta, unsigned short* __restrict__ out) {
  const int row = blockIdx.x;
  const int t = threadIdx.x;
  const int w = t >> 6, lane = t & 63;
  const float4 v = ((const float4*)(x + (size_t)row * DM))[t];

  float s = v.x + v.y + v.z + v.w;
#pragma unroll
  for (int off = 32; off; off >>= 1) s += __shfl_xor(s, off, 64);
  __shared__ float red1[4];
  __shared__ float red2[4];
  if (lane == 0) red1[w] = s;
  __syncthreads();
  const float mu = (red1[0] + red1[1] + red1[2] + red1[3]) * (1.f / 1024.f);

  const float dx = v.x - mu, dy = v.y - mu, dz = v.z - mu, dw = v.w - mu;
  float sq = dx * dx + dy * dy + dz * dz + dw * dw;
#pragma unroll
  for (int off = 32; off; off >>= 1) sq += __shfl_xor(sq, off, 64);
  if (lane == 0) red2[w] = sq;
  __syncthreads();
  const float var = (red2[0] + red2[1] + red2[2] + red2[3]) * (1.f / 1023.f);
  const float rstd = rsqrtf(var + 1e-6f);

  const float4 a = ((const float4*)alpha)[t];
  const float4 b = ((const float4*)beta)[t];
  const float o0 = dx * rstd * a.x + b.x;
  const float o1 = dy * rstd * a.y + b.y;
  const float o2 = dz * rstd * a.z + b.z;
  const float o3 = dw * rstd * a.w + b.w;
  uint2 ov;
  ov.x = cvt_pk_bf16(o0, o1);
  ov.y = cvt_pk_bf16(o2, o3);
  *(uint2*)(out + (size_t)row * DM + 4 * t) = ov;
}

// ---------------- shared epilogue (MODE 1 / MODE 2) -------------------------
template <int MODE>
__device__ __forceinline__ void epi_store(int m, int n, float v, int Nout,
                                          unsigned short* __restrict__ obf, float* of,
                                          const float* res,
                                          const float* __restrict__ bias0) {
  if (MODE == 1) {
    v += bias0[n] + res[(size_t)m * Nout + n];
    of[(size_t)m * Nout + n] = v;
  } else {
    v += bias0[n];
    const float gv = 0.5f * v * (1.0f + erf_fast(v * 0.70710678118654752f));
    obf[(size_t)m * Nout + n] = f2bf(gv);
  }
}

// ---- XCD supertile mapping (shared): gridDim.y == 64 -----------------------
__device__ __forceinline__ void supertile_map(int& m0, int& n0) {
  const int L = blockIdx.y * gridDim.x + blockIdx.x;
  const int nwg = gridDim.x * gridDim.y;
  const int chunk = nwg >> 3;
  const int ncols = chunk >> 6;
  const int denom = ncols << 3;
  const int xcd = L & 7, li = L >> 3;
  const int sst = li / denom, wst = li % denom;
  const int by = sst * 8 + (wst & 7);
  const int bx = xcd * ncols + (wst >> 3);
  m0 = by * 128; n0 = bx * 128;
}

// ---------------- 128x128x64 GEMM, DOUBLE-buffered (r8) ---------------------
// For grids that cap at 2 blocks/CU anyway (O-proj, MLP2). 64KB LDS.
template <int MODE>
__global__ __launch_bounds__(256, 2)
void gemmk(const unsigned short* __restrict__ A, const unsigned short* __restrict__ B,
           int K, int Nout,
           unsigned short* __restrict__ obf, float* of, const float* res,
           const float* __restrict__ bias0, const float* __restrict__ bias1,
           const float* __restrict__ bias2) {
  __shared__ __attribute__((aligned(16))) unsigned short sA[2][128 * 64];
  __shared__ __attribute__((aligned(16))) unsigned short sB[2][128 * 64];
  const int t = threadIdx.x;
  const int lane = t & 63, wid = t >> 6;
  const int g = lane >> 4, r = lane & 15;
  const int wm = wid >> 1, wn = wid & 1;

  int m0, n0;
  supertile_map(m0, n0);

  const unsigned short* Ab = A + (size_t)m0 * K;
  const unsigned short* Bb = B + (size_t)n0 * K;

  const int rb = r & 7;
  const int slot0 = (g ^ rb) * 16;
  const int slot1 = ((4 + g) ^ rb) * 16;

  f32x4 acc[4][4];
#pragma unroll
  for (int i2 = 0; i2 < 4; ++i2)
#pragma unroll
    for (int j = 0; j < 4; ++j) acc[i2][j] = (f32x4){0.f, 0.f, 0.f, 0.f};

  auto stage = [&](int buf, int kt) {
#pragma unroll
    for (int s2 = 0; s2 < 4; ++s2) {
      const int f = s2 * 256 + t;
      const int row = f >> 3, c = f & 7;
      const int u = c ^ (row & 7);
      gload16(Ab + (size_t)row * K + kt * 64 + u * 8, &sA[buf][(size_t)row * 64 + c * 8]);
      gload16(Bb + (size_t)row * K + kt * 64 + u * 8, &sB[buf][(size_t)row * 64 + c * 8]);
    }
  };

  const int NT = K >> 6;
  stage(0, 0);
  stage(1, (NT > 1) ? 1 : 0);
  VMCNT8();
  BAR();

  for (int tt = 0; tt < NT; ++tt) {
    const int cur = tt & 1;
    const char* sAc = (const char*)&sA[cur][0];
    const char* sBc = (const char*)&sB[cur][0];

    s16x8 av[4][2], bv[4][2];
#pragma unroll
    for (int i2 = 0; i2 < 4; ++i2) {
      const int rbyte = (wm * 64 + i2 * 16 + r) * 128;
      av[i2][0] = *(const s16x8*)(sAc + rbyte + slot0);
      av[i2][1] = *(const s16x8*)(sAc + rbyte + slot1);
    }
#pragma unroll
    for (int n = 0; n < 4; ++n) {
      const int rbyte = (wn * 64 + n * 16 + r) * 128;
      bv[n][0] = *(const s16x8*)(sBc + rbyte + slot0);
      bv[n][1] = *(const s16x8*)(sBc + rbyte + slot1);
    }
#pragma unroll
    for (int i2 = 0; i2 < 4; ++i2)
#pragma unroll
      for (int n = 0; n < 4; ++n) {
        acc[i2][n] = MFMA16(av[i2][0], bv[n][0], acc[i2][n], 0, 0, 0);
        acc[i2][n] = MFMA16(av[i2][1], bv[n][1], acc[i2][n], 0, 0, 0);
      }

    BAR();
    const int tp2 = (tt + 2 < NT) ? tt + 2 : NT - 1;
    stage(cur, tp2);
    VMCNT8();
    BAR();
  }

  VMCNT0();

#pragma unroll
  for (int i2 = 0; i2 < 4; ++i2)
#pragma unroll
    for (int j = 0; j < 4; ++j) {
      const int m = m0 + wm * 64 + i2 * 16 + 4 * g + j;
#pragma unroll
      for (int nf = 0; nf < 4; ++nf) {
        const int n = n0 + wn * 64 + nf * 16 + r;
        epi_store<MODE>(m, n, acc[i2][nf][j], Nout, obf, of, res, bias0);
      }
    }
}

// ---------------- 128x128x64 GEMM, SINGLE-buffered, 4 blocks/CU -------------
// 32KB LDS; TLP (3 partner blocks) covers the per-tile vmcnt(0) latency.
// For grids >= 1024 wgs (QKV MODE 0, MLP1 MODE 2).
template <int MODE>
__global__ __launch_bounds__(256, 4)
void gemms(const unsigned short* __restrict__ A, const unsigned short* __restrict__ B,
           int K, int Nout,
           unsigned short* __restrict__ obf, float* of, const float* res,
           const float* __restrict__ bias0, const float* __restrict__ bias1,
           const float* __restrict__ bias2) {
  __shared__ __attribute__((aligned(16))) unsigned short sM[2][128 * 64]; // [0]=A [1]=B
  const int t = threadIdx.x;
  const int lane = t & 63, wid = t >> 6;
  const int g = lane >> 4, r = lane & 15;
  const int wm = wid >> 1, wn = wid & 1;

  int m0, n0;
  supertile_map(m0, n0);

  const unsigned short* Ab = A + (size_t)m0 * K;
  const unsigned short* Bb = B + (size_t)n0 * K;

  const int rb = r & 7;
  const int slot0 = (g ^ rb) * 16;
  const int slot1 = ((4 + g) ^ rb) * 16;

  f32x4 acc[4][4];
#pragma unroll
  for (int i2 = 0; i2 < 4; ++i2)
#pragma unroll
    for (int j = 0; j < 4; ++j) acc[i2][j] = (f32x4){0.f, 0.f, 0.f, 0.f};

  auto stage = [&](int kt) {
#pragma unroll
    for (int s2 = 0; s2 < 4; ++s2) {
      const int f = s2 * 256 + t;
      const int row = f >> 3, c = f & 7;
      const int u = c ^ (row & 7);
      gload16(Ab + (size_t)row * K + kt * 64 + u * 8, &sM[0][(size_t)row * 64 + c * 8]);
      gload16(Bb + (size_t)row * K + kt * 64 + u * 8, &sM[1][(size_t)row * 64 + c * 8]);
    }
  };

  const int NT = K >> 6;
  stage(0);
  VMCNT0();
  BAR();

  for (int tt = 0; tt < NT; ++tt) {
    const char* sAc = (const char*)&sM[0][0];
    const char* sBc = (const char*)&sM[1][0];

    s16x8 av[4][2], bv[4][2];
#pragma unroll
    for (int i2 = 0; i2 < 4; ++i2) {
      const int rbyte = (wm * 64 + i2 * 16 + r) * 128;
      av[i2][0] = *(const s16x8*)(sAc + rbyte + slot0);
      av[i2][1] = *(const s16x8*)(sAc + rbyte + slot1);
    }
#pragma unroll
    for (int n = 0; n < 4; ++n) {
      const int rbyte = (wn * 64 + n * 16 + r) * 128;
      bv[n][0] = *(const s16x8*)(sBc + rbyte + slot0);
      bv[n][1] = *(const s16x8*)(sBc + rbyte + slot1);
    }
#pragma unroll
    for (int i2 = 0; i2 < 4; ++i2)
#pragma unroll
      for (int n = 0; n < 4; ++n) {
        acc[i2][n] = MFMA16(av[i2][0], bv[n][0], acc[i2][n], 0, 0, 0);
        acc[i2][n] = MFMA16(av[i2][1], bv[n][1], acc[i2][n], 0, 0, 0);
      }

    BAR();                                    // all waves done reading sM
    if (tt + 1 < NT) stage(tt + 1);           // next tile (skip on last)
    VMCNT0();                                 // own DMAs landed
    BAR();                                    // all waves' DMAs landed
  }
  // loop exit: VMCNT0+BAR already executed -> LDS reusable, DMA quiet

  if (MODE == 0) {
    const int which = n0 >> 10;
    const int hn = ((n0 & 1023) + wn * 64) >> 6;
    const int mwave = m0 + wm * 64;
    const int b = mwave >> 10, s_wb = mwave & 1023;
    if (which == 2) {
      // V: transpose 64x64 wave-tile in this wave's 8KB LDS slice
      unsigned short* tl = (unsigned short*)&sM[0][0] + (size_t)wid * (64 * 64);
#pragma unroll
      for (int i2 = 0; i2 < 4; ++i2)
#pragma unroll
        for (int nf = 0; nf < 4; ++nf) {
          const int d = nf * 16 + r;
          const float bias = bias2[hn * 64 + d];
          s16x4 o;
#pragma unroll
          for (int j = 0; j < 4; ++j) o[j] = (short)f2bf(acc[i2][nf][j] + bias);
          *(s16x4*)&tl[d * 64 + i2 * 16 + 4 * g] = o;
        }
      unsigned short* vout = obf + (size_t)2 * (M_TOTAL * DM) +
                             ((size_t)(b * NH + hn) * DH) * SEQ + s_wb;
#pragma unroll
      for (int p2 = 0; p2 < 16; ++p2) {
        const int d = p2 * 4 + g;
        const s16x4 v = *(const s16x4*)&tl[d * 64 + 4 * r];
        *(s16x4*)(vout + (size_t)d * SEQ + 4 * r) = v;
      }
    } else {
#pragma unroll
      for (int i2 = 0; i2 < 4; ++i2)
#pragma unroll
        for (int nf = 0; nf < 4; ++nf) {
          const int d = nf * 16 + r;
          const float bias = (which == 0) ? bias0[hn * 64 + d] : bias1[hn * 64 + d];
          const int s_base = s_wb + i2 * 16 + 4 * g;
#pragma unroll
          for (int j = 0; j < 4; ++j) {
            float v = acc[i2][nf][j] + bias;
            if (which == 0) v *= 0.1803368801f;  // 1/8 * log2(e): exp2-domain scores
            obf[(size_t)which * (M_TOTAL * DM) +
                (((size_t)(b * NH + hn) * SEQ + (s_base + j)) * DH + d)] = f2bf(v);
          }
        }
    }
  } else {
#pragma unroll
    for (int i2 = 0; i2 < 4; ++i2)
#pragma unroll
      for (int j = 0; j < 4; ++j) {
        const int m = m0 + wm * 64 + i2 * 16 + 4 * g + j;
#pragma unroll
        for (int nf = 0; nf < 4; ++nf) {
          const int n = n0 + wn * 64 + nf * 16 + r;
          epi_store<MODE>(m, n, acc[i2][nf][j], Nout, obf, of, res, bias0);
        }
      }
  }
}

// ---------------- flash attention (swapped-QK, swizzled LDS, prefetch) ------
// Q pre-scaled by (1/8)*log2(e) -> softmax in exp2 domain (p = 2^(s-m)).
// V already transposed: VT[bh][d][s] at QKV slice 2.
// defer-max (T13): skip O-rescale when per-tile max growth <= 8 (log2 units).
__global__ __launch_bounds__(256)
void attn_kernel(const unsigned short* __restrict__ QKV,
                 unsigned short* __restrict__ O) {
  const unsigned short* Qg = QKV;
  const unsigned short* Kg = QKV + (size_t)M_TOTAL * DM;
  const unsigned short* VTg = QKV + 2 * (size_t)M_TOTAL * DM;
  const int bh = blockIdx.y;
  const int q0 = blockIdx.x * 64;
  const int t = threadIdx.x, w = t >> 6, lane = t & 63;
  const int g = lane >> 4, r = lane & 15;
  const unsigned short* Qb = Qg + (size_t)bh * SEQ * DH;
  const unsigned short* Kb = Kg + (size_t)bh * SEQ * DH;
  const unsigned short* VTb = VTg + (size_t)bh * DH * SEQ;

  __shared__ __attribute__((aligned(16))) unsigned short sK[2][64 * 64];
  __shared__ __attribute__((aligned(16))) unsigned short sV[2][64 * 64];

  s16x8 qf[2];
  {
    const unsigned short* qrow = Qb + (size_t)(q0 + w * 16 + r) * DH;
    qf[0] = *(const s16x8*)(qrow + g * 8);
    qf[1] = *(const s16x8*)(qrow + 32 + g * 8);
  }

  f32x4 oacc[4];
#pragma unroll
  for (int i = 0; i < 4; ++i) oacc[i] = (f32x4){0.f, 0.f, 0.f, 0.f};
  float mrun = -1e30f, lrun = 0.f;

  auto stage = [&](int buf, int kt) {
#pragma unroll
    for (int s2 = 0; s2 < 2; ++s2) {
      const int f = s2 * 256 + t;
      const int row = f >> 3, u = (f & 7) ^ (row & 7);
      gload16(Kb + (size_t)(kt * 64 + row) * DH + u * 8, &sK[buf][f * 8]);
      gload16(VTb + (size_t)row * SEQ + kt * 64 + u * 8, &sV[buf][f * 8]);
    }
  };

  stage(0, 0);
  __syncthreads();

  for (int kt = 0; kt < SEQ / 64; ++kt) {
    const int cur = kt & 1;
    if (kt < SEQ / 64 - 1) stage(cur ^ 1, kt + 1);

    f32x4 sc[4];
#pragma unroll
    for (int nf = 0; nf < 4; ++nf) {
      sc[nf] = (f32x4){0.f, 0.f, 0.f, 0.f};
      const int rowk = nf * 16 + r;
#pragma unroll
      for (int ks = 0; ks < 2; ++ks) {
        const int u = (4 * ks + g) ^ (rowk & 7);
        const s16x8 kf = *(const s16x8*)&sK[cur][rowk * 64 + u * 8];
        sc[nf] = __builtin_amdgcn_mfma_f32_16x16x32_bf16(kf, qf[ks], sc[nf], 0, 0, 0);
      }
    }

    float pm = -1e30f;
#pragma unroll
    for (int nf = 0; nf < 4; ++nf)
#pragma unroll
      for (int j = 0; j < 4; ++j) pm = fmaxf(pm, sc[nf][j]);
    pm = fmaxf(pm, __shfl_xor(pm, 16, 64));
    pm = fmaxf(pm, __shfl_xor(pm, 32, 64));

    if (!__all(pm - mrun <= 8.0f)) {
      const float mnew = fmaxf(mrun, pm);
      const float alpha = exp2_fast(mrun - mnew);
      mrun = mnew;
      lrun *= alpha;
      float ao[4];
#pragma unroll
      for (int j = 0; j < 4; ++j) ao[j] = __shfl(alpha, 4 * g + j, 64);
#pragma unroll
      for (int nf2 = 0; nf2 < 4; ++nf2)
#pragma unroll
        for (int j = 0; j < 4; ++j) oacc[nf2][j] *= ao[j];
    }

    float p[4][4];
    float ps = 0.f;
#pragma unroll
    for (int nf = 0; nf < 4; ++nf)
#pragma unroll
      for (int j = 0; j < 4; ++j) {
        p[nf][j] = exp2_fast(sc[nf][j] - mrun);   // bounded by 2^8
        ps += p[nf][j];
      }
    ps += __shfl_xor(ps, 16, 64);
    ps += __shfl_xor(ps, 32, 64);
    lrun += ps;

    unsigned int pk[4][2];
#pragma unroll
    for (int nf = 0; nf < 4; ++nf)
#pragma unroll
      for (int jp = 0; jp < 2; ++jp)
        pk[nf][jp] = cvt_pk_bf16(p[nf][2 * jp], p[nf][2 * jp + 1]);

    unsigned int pa32[2][4];
#pragma unroll
    for (int ks = 0; ks < 2; ++ks)
#pragma unroll
      for (int q2 = 0; q2 < 4; ++q2) {
        const int src = r + 32 * (g & 1) + 16 * (q2 >> 1);
        const unsigned int a = (unsigned int)__shfl((int)pk[2 * ks][q2 & 1], src, 64);
        const unsigned int b = (unsigned int)__shfl((int)pk[2 * ks + 1][q2 & 1], src, 64);
        pa32[ks][q2] = (g >> 1) ? b : a;
      }
    s16x8 pa[2];
#pragma unroll
    for (int ks = 0; ks < 2; ++ks) {
      u32x4 pw;
      pw[0] = pa32[ks][0]; pw[1] = pa32[ks][1];
      pw[2] = pa32[ks][2]; pw[3] = pa32[ks][3];
      pa[ks] = __builtin_bit_cast(s16x8, pw);
    }

#pragma unroll
    for (int nf2 = 0; nf2 < 4; ++nf2) {
      const int rowd = nf2 * 16 + r;
#pragma unroll
      for (int ks = 0; ks < 2; ++ks) {
        const int u = (4 * ks + g) ^ (rowd & 7);
        const s16x8 vb = *(const s16x8*)&sV[cur][rowd * 64 + u * 8];
        oacc[nf2] = __builtin_amdgcn_mfma_f32_16x16x32_bf16(pa[ks], vb, oacc[nf2], 0, 0, 0);
      }
    }
    __syncthreads();
  }

  const int b = bh >> 4, h = bh & 15;
  const float linv = 1.f / lrun;
#pragma unroll
  for (int j = 0; j < 4; ++j) {
    const float lo = __shfl(linv, 4 * g + j, 64);
    const int q = q0 + w * 16 + 4 * g + j;
    const size_t orow = ((size_t)(b * SEQ + q)) * DM + h * DH;
#pragma unroll
    for (int nf2 = 0; nf2 < 4; ++nf2)
      O[orow + nf2 * 16 + r] = f2bf(oacc[nf2][j] * lo);
  }
}

// ---------------------------------------------------------------------------
extern "C" void kernel_launch(void* const* d_in, const int* in_sizes, int n_in,
                              void* d_out, int out_size, void* d_ws, size_t ws_size,
                              hipStream_t stream) {
  const float* x   = (const float*)d_in[0];
  const float* al1 = (const float*)d_in[1];
  const float* be1 = (const float*)d_in[2];
  const float* al2 = (const float*)d_in[3];
  const float* be2 = (const float*)d_in[4];
  const float* wq  = (const float*)d_in[5];
  const float* bq  = (const float*)d_in[6];
  const float* wk  = (const float*)d_in[7];
  const float* bk  = (const float*)d_in[8];
  const float* wv  = (const float*)d_in[9];
  const float* bv  = (const float*)d_in[10];
  const float* wo  = (const float*)d_in[11];
  const float* bo  = (const float*)d_in[12];
  const float* w1  = (const float*)d_in[13];
  const float* b1  = (const float*)d_in[14];
  const float* w2  = (const float*)d_in[15];
  const float* b2  = (const float*)d_in[16];
  float* dout = (float*)d_out;

  unsigned short* ws = (unsigned short*)d_ws;
  size_t off = 0;
  auto alloc = [&](size_t n) { unsigned short* p = ws + off; off += n; return p; };
  unsigned short* WTqkv = alloc((size_t)3072 * 1024);
  unsigned short* WTo   = alloc((size_t)1024 * 1024);
  unsigned short* WT1   = alloc((size_t)4096 * 1024);
  unsigned short* WT2   = alloc((size_t)1024 * 4096);
  unsigned short* xn    = alloc((size_t)M_TOTAL * DM);
  unsigned short* QKVb  = alloc((size_t)3 * M_TOTAL * DM);  // Q, K, V^T slices
  unsigned short* attn  = alloc((size_t)M_TOTAL * DM);
  unsigned short* h1    = alloc((size_t)M_TOTAL * HID);
  (void)ws_size; (void)in_sizes; (void)n_in; (void)out_size;

  // all 6 weight transposes in one launch
  tcast_all<<<12288, dim3(32, 8), 0, stream>>>(wq, wk, wv, wo, w1, w2,
                                               WTqkv, WTo, WT1, WT2);

  // LN1: x -> xn (bf16)
  ln_kernel<<<M_TOTAL, 256, 0, stream>>>(x, al1, be1, xn);
  // QKV projection: 1536 wgs -> single-buffered 4-blocks/CU kernel
  gemms<0><<<dim3(24, 64), 256, 0, stream>>>(xn, WTqkv, 1024, 3072,
                                             QKVb, nullptr, nullptr, bq, bk, bv);
  // attention (reads Q, K, V^T from QKVb)
  attn_kernel<<<dim3(16, 128), 256, 0, stream>>>(QKVb, attn);
  // O projection + residual: 512 wgs -> double-buffered kernel
  gemmk<1><<<dim3(8, 64), 256, 0, stream>>>(attn, WTo, 1024, 1024,
                                            nullptr, dout, x, bo, nullptr, nullptr);
  // LN2: dout -> xn (bf16)
  ln_kernel<<<M_TOTAL, 256, 0, stream>>>(dout, al2, be2, xn);
  // MLP1 + GELU: 2048 wgs -> single-buffered 4-blocks/CU kernel
  gemms<2><<<dim3(32, 64), 256, 0, stream>>>(xn, WT1, 1024, 4096,
                                             h1, nullptr, nullptr, b1, nullptr, nullptr);
  // MLP2 + residual: 512 wgs -> double-buffered kernel
  gemmk<1><<<dim3(8, 64), 256, 0, stream>>>(h1, WT2, 4096, 1024,
                                            nullptr, dout, dout, b2, nullptr, nullptr);
}

// Round 15
// 395.590 us; speedup vs baseline: 1.0477x; 1.0477x over previous
//
#include <hip/hip_runtime.h>
#include <stdint.h>

typedef float f32x4 __attribute__((ext_vector_type(4)));
typedef short s16x8 __attribute__((ext_vector_type(8)));
typedef short s16x4 __attribute__((ext_vector_type(4)));
typedef unsigned int u32x4 __attribute__((ext_vector_type(4)));

#define M_TOTAL 8192
#define DM 1024
#define HID 4096
#define SEQ 1024
#define NH 16
#define DH 64

#define BAR() __builtin_amdgcn_s_barrier()
#define VMCNT8() do { asm volatile("s_waitcnt vmcnt(8)" ::: "memory"); __builtin_amdgcn_sched_barrier(0); } while (0)
#define VMCNT0() do { asm volatile("s_waitcnt vmcnt(0)" ::: "memory"); __builtin_amdgcn_sched_barrier(0); } while (0)
#define MFMA16 __builtin_amdgcn_mfma_f32_16x16x32_bf16

__device__ __forceinline__ unsigned short f2bf(float f) {
  unsigned int u = __float_as_uint(f);
  u = (u + 0x7fffu + ((u >> 16) & 1u)) >> 16;
  return (unsigned short)u;
}

// packed f32x2 -> bf16x2 in one instruction (gfx950)
__device__ __forceinline__ unsigned int cvt_pk_bf16(float lo, float hi) {
  unsigned int r;
  asm("v_cvt_pk_bf16_f32 %0, %1, %2" : "=v"(r) : "v"(lo), "v"(hi));
  return r;
}

// raw v_exp_f32: D = 2^S0
__device__ __forceinline__ float exp2_fast(float x) {
  float r;
  asm("v_exp_f32 %0, %1" : "=v"(r) : "v"(x));
  return r;
}

__device__ __forceinline__ void gload16(const void* g, void* l) {
  __builtin_amdgcn_global_load_lds((__attribute__((address_space(1))) void*)g,
                                   (__attribute__((address_space(3))) void*)l,
                                   16, 0, 0);
}

// fast erf (Abramowitz-Stegun 7.1.26, |err| <= 1.5e-7)
__device__ __forceinline__ float erf_fast(float z) {
  const float az = fabsf(z);
  const float tt = 1.0f / fmaf(0.3275911f, az, 1.0f);
  float poly = fmaf(1.061405429f, tt, -1.453152027f);
  poly = fmaf(poly, tt, 1.421413741f);
  poly = fmaf(poly, tt, -0.284496736f);
  poly = fmaf(poly, tt, 0.254829592f);
  poly *= tt;
  const float e = __expf(-az * az);
  const float r = 1.0f - poly * e;
  return (z < 0.f) ? -r : r;
}

// ------- batched transpose+cast f32 -> bf16 for all 6 weight matrices -------
__global__ void tcast_all(const float* __restrict__ wq, const float* __restrict__ wk,
                          const float* __restrict__ wv, const float* __restrict__ wo,
                          const float* __restrict__ w1, const float* __restrict__ w2,
                          unsigned short* __restrict__ WTqkv, unsigned short* __restrict__ WTo,
                          unsigned short* __restrict__ WT1, unsigned short* __restrict__ WT2) {
  __shared__ float tile[32][33];
  const int b = blockIdx.x;
  const float* W;
  unsigned short* WT;
  int K, N, bn, bk;
  if (b < 4096) {
    const int j = b >> 10, t2 = b & 1023;
    K = 1024; N = 1024;
    bn = t2 & 31; bk = t2 >> 5;
    W = (j == 0) ? wq : (j == 1) ? wk : (j == 2) ? wv : wo;
    WT = (j < 3) ? (WTqkv + (size_t)j * 1024 * 1024) : WTo;
  } else if (b < 8192) {
    const int t2 = b - 4096;
    K = 1024; N = 4096;
    bn = t2 & 127; bk = t2 >> 7;
    W = w1; WT = WT1;
  } else {
    const int t2 = b - 8192;
    K = 4096; N = 1024;
    bn = t2 & 31; bk = t2 >> 5;
    W = w2; WT = WT2;
  }
  const int tx = threadIdx.x, ty = threadIdx.y;  // 32 x 8
#pragma unroll
  for (int i = 0; i < 32; i += 8)
    tile[ty + i][tx] = W[(size_t)(bk * 32 + ty + i) * N + bn * 32 + tx];
  __syncthreads();
#pragma unroll
  for (int i = 0; i < 32; i += 8)
    WT[(size_t)(bn * 32 + ty + i) * K + bk * 32 + tx] = f2bf(tile[tx][ty + i]);
}

// ---------------- LayerNorm (ddof=1) f32 in -> bf16 out ---------------------
__global__ __launch_bounds__(256)
void ln_kernel(const float* __restrict__ x, const float* __restrict__ alpha,
               const float* __restrict__ beta, unsigned short* __restrict__ out) {
  const int row = blockIdx.x;
  const int t = threadIdx.x;
  const int w = t >> 6, lane = t & 63;
  const float4 v = ((const float4*)(x + (size_t)row * DM))[t];

  float s = v.x + v.y + v.z + v.w;
#pragma unroll
  for (int off = 32; off; off >>= 1) s += __shfl_xor(s, off, 64);
  __shared__ float red1[4];
  __shared__ float red2[4];
  if (lane == 0) red1[w] = s;
  __syncthreads();
  const float mu = (red1[0] + red1[1] + red1[2] + red1[3]) * (1.f / 1024.f);

  const float dx = v.x - mu, dy = v.y - mu, dz = v.z - mu, dw = v.w - mu;
  float sq = dx * dx + dy * dy + dz * dz + dw * dw;
#pragma unroll
  for (int off = 32; off; off >>= 1) sq += __shfl_xor(sq, off, 64);
  if (lane == 0) red2[w] = sq;
  __syncthreads();
  const float var = (red2[0] + red2[1] + red2[2] + red2[3]) * (1.f / 1023.f);
  const float rstd = rsqrtf(var + 1e-6f);

  const float4 a = ((const float4*)alpha)[t];
  const float4 b = ((const float4*)beta)[t];
  const float o0 = dx * rstd * a.x + b.x;
  const float o1 = dy * rstd * a.y + b.y;
  const float o2 = dz * rstd * a.z + b.z;
  const float o3 = dw * rstd * a.w + b.w;
  uint2 ov;
  ov.x = cvt_pk_bf16(o0, o1);
  ov.y = cvt_pk_bf16(o2, o3);
  *(uint2*)(out + (size_t)row * DM + 4 * t) = ov;
}

// ---------------- shared epilogue (MODE 1 / MODE 2) -------------------------
template <int MODE>
__device__ __forceinline__ void epi_store(int m, int n, float v, int Nout,
                                          unsigned short* __restrict__ obf, float* of,
                                          const float* res,
                                          const float* __restrict__ bias0) {
  if (MODE == 1) {
    v += bias0[n] + res[(size_t)m * Nout + n];
    of[(size_t)m * Nout + n] = v;
  } else {
    v += bias0[n];
    const float gv = 0.5f * v * (1.0f + erf_fast(v * 0.70710678118654752f));
    obf[(size_t)m * Nout + n] = f2bf(gv);
  }
}

// ---- XCD supertile mapping (shared): gridDim.y == 64 -----------------------
__device__ __forceinline__ void supertile_map(int& m0, int& n0) {
  const int L = blockIdx.y * gridDim.x + blockIdx.x;
  const int nwg = gridDim.x * gridDim.y;
  const int chunk = nwg >> 3;
  const int ncols = chunk >> 6;
  const int denom = ncols << 3;
  const int xcd = L & 7, li = L >> 3;
  const int sst = li / denom, wst = li % denom;
  const int by = sst * 8 + (wst & 7);
  const int bx = xcd * ncols + (wst >> 3);
  m0 = by * 128; n0 = bx * 128;
}

// ---------------- 128x128x64 GEMM, DOUBLE-buffered (r8) ---------------------
// For grids that cap at 2 blocks/CU anyway (O-proj, MLP2). 64KB LDS.
template <int MODE>
__global__ __launch_bounds__(256, 2)
void gemmk(const unsigned short* __restrict__ A, const unsigned short* __restrict__ B,
           int K, int Nout,
           unsigned short* __restrict__ obf, float* of, const float* res,
           const float* __restrict__ bias0, const float* __restrict__ bias1,
           const float* __restrict__ bias2) {
  __shared__ __attribute__((aligned(16))) unsigned short sA[2][128 * 64];
  __shared__ __attribute__((aligned(16))) unsigned short sB[2][128 * 64];
  const int t = threadIdx.x;
  const int lane = t & 63, wid = t >> 6;
  const int g = lane >> 4, r = lane & 15;
  const int wm = wid >> 1, wn = wid & 1;

  int m0, n0;
  supertile_map(m0, n0);

  const unsigned short* Ab = A + (size_t)m0 * K;
  const unsigned short* Bb = B + (size_t)n0 * K;

  const int rb = r & 7;
  const int slot0 = (g ^ rb) * 16;
  const int slot1 = ((4 + g) ^ rb) * 16;

  f32x4 acc[4][4];
#pragma unroll
  for (int i2 = 0; i2 < 4; ++i2)
#pragma unroll
    for (int j = 0; j < 4; ++j) acc[i2][j] = (f32x4){0.f, 0.f, 0.f, 0.f};

  auto stage = [&](int buf, int kt) {
#pragma unroll
    for (int s2 = 0; s2 < 4; ++s2) {
      const int f = s2 * 256 + t;
      const int row = f >> 3, c = f & 7;
      const int u = c ^ (row & 7);
      gload16(Ab + (size_t)row * K + kt * 64 + u * 8, &sA[buf][(size_t)row * 64 + c * 8]);
      gload16(Bb + (size_t)row * K + kt * 64 + u * 8, &sB[buf][(size_t)row * 64 + c * 8]);
    }
  };

  const int NT = K >> 6;
  stage(0, 0);
  stage(1, (NT > 1) ? 1 : 0);
  VMCNT8();
  BAR();

  for (int tt = 0; tt < NT; ++tt) {
    const int cur = tt & 1;
    const char* sAc = (const char*)&sA[cur][0];
    const char* sBc = (const char*)&sB[cur][0];

    s16x8 av[4][2], bv[4][2];
#pragma unroll
    for (int i2 = 0; i2 < 4; ++i2) {
      const int rbyte = (wm * 64 + i2 * 16 + r) * 128;
      av[i2][0] = *(const s16x8*)(sAc + rbyte + slot0);
      av[i2][1] = *(const s16x8*)(sAc + rbyte + slot1);
    }
#pragma unroll
    for (int n = 0; n < 4; ++n) {
      const int rbyte = (wn * 64 + n * 16 + r) * 128;
      bv[n][0] = *(const s16x8*)(sBc + rbyte + slot0);
      bv[n][1] = *(const s16x8*)(sBc + rbyte + slot1);
    }
#pragma unroll
    for (int i2 = 0; i2 < 4; ++i2)
#pragma unroll
      for (int n = 0; n < 4; ++n) {
        acc[i2][n] = MFMA16(av[i2][0], bv[n][0], acc[i2][n], 0, 0, 0);
        acc[i2][n] = MFMA16(av[i2][1], bv[n][1], acc[i2][n], 0, 0, 0);
      }

    BAR();
    const int tp2 = (tt + 2 < NT) ? tt + 2 : NT - 1;
    stage(cur, tp2);
    VMCNT8();
    BAR();
  }

  VMCNT0();

#pragma unroll
  for (int i2 = 0; i2 < 4; ++i2)
#pragma unroll
    for (int j = 0; j < 4; ++j) {
      const int m = m0 + wm * 64 + i2 * 16 + 4 * g + j;
#pragma unroll
      for (int nf = 0; nf < 4; ++nf) {
        const int n = n0 + wn * 64 + nf * 16 + r;
        epi_store<MODE>(m, n, acc[i2][nf][j], Nout, obf, of, res, bias0);
      }
    }
}

// ---------------- 128x128x64 GEMM, SINGLE-buffered, 4 blocks/CU -------------
// 32KB LDS; TLP (3 partner blocks) covers the per-tile vmcnt(0) latency.
// For grids >= 1024 wgs (QKV MODE 0, MLP1 MODE 2).
template <int MODE>
__global__ __launch_bounds__(256, 4)
void gemms(const unsigned short* __restrict__ A, const unsigned short* __restrict__ B,
           int K, int Nout,
           unsigned short* __restrict__ obf, float* of, const float* res,
           const float* __restrict__ bias0, const float* __restrict__ bias1,
           const float* __restrict__ bias2) {
  __shared__ __attribute__((aligned(16))) unsigned short sM[2][128 * 64]; // [0]=A [1]=B
  const int t = threadIdx.x;
  const int lane = t & 63, wid = t >> 6;
  const int g = lane >> 4, r = lane & 15;
  const int wm = wid >> 1, wn = wid & 1;

  int m0, n0;
  supertile_map(m0, n0);

  const unsigned short* Ab = A + (size_t)m0 * K;
  const unsigned short* Bb = B + (size_t)n0 * K;

  const int rb = r & 7;
  const int slot0 = (g ^ rb) * 16;
  const int slot1 = ((4 + g) ^ rb) * 16;

  f32x4 acc[4][4];
#pragma unroll
  for (int i2 = 0; i2 < 4; ++i2)
#pragma unroll
    for (int j = 0; j < 4; ++j) acc[i2][j] = (f32x4){0.f, 0.f, 0.f, 0.f};

  auto stage = [&](int kt) {
#pragma unroll
    for (int s2 = 0; s2 < 4; ++s2) {
      const int f = s2 * 256 + t;
      const int row = f >> 3, c = f & 7;
      const int u = c ^ (row & 7);
      gload16(Ab + (size_t)row * K + kt * 64 + u * 8, &sM[0][(size_t)row * 64 + c * 8]);
      gload16(Bb + (size_t)row * K + kt * 64 + u * 8, &sM[1][(size_t)row * 64 + c * 8]);
    }
  };

  const int NT = K >> 6;
  stage(0);
  VMCNT0();
  BAR();

  for (int tt = 0; tt < NT; ++tt) {
    const char* sAc = (const char*)&sM[0][0];
    const char* sBc = (const char*)&sM[1][0];

    s16x8 av[4][2], bv[4][2];
#pragma unroll
    for (int i2 = 0; i2 < 4; ++i2) {
      const int rbyte = (wm * 64 + i2 * 16 + r) * 128;
      av[i2][0] = *(const s16x8*)(sAc + rbyte + slot0);
      av[i2][1] = *(const s16x8*)(sAc + rbyte + slot1);
    }
#pragma unroll
    for (int n = 0; n < 4; ++n) {
      const int rbyte = (wn * 64 + n * 16 + r) * 128;
      bv[n][0] = *(const s16x8*)(sBc + rbyte + slot0);
      bv[n][1] = *(const s16x8*)(sBc + rbyte + slot1);
    }
#pragma unroll
    for (int i2 = 0; i2 < 4; ++i2)
#pragma unroll
      for (int n = 0; n < 4; ++n) {
        acc[i2][n] = MFMA16(av[i2][0], bv[n][0], acc[i2][n], 0, 0, 0);
        acc[i2][n] = MFMA16(av[i2][1], bv[n][1], acc[i2][n], 0, 0, 0);
      }

    BAR();                                    // all waves done reading sM
    stage((tt + 1 < NT) ? tt + 1 : tt);       // unconditional clamped re-stage
    VMCNT0();                                 // own DMAs landed
    BAR();                                    // all waves' DMAs landed
  }
  // loop exit: VMCNT0+BAR already executed -> LDS reusable, DMA quiet

  if (MODE == 0) {
    const int which = n0 >> 10;
    const int hn = ((n0 & 1023) + wn * 64) >> 6;
    const int mwave = m0 + wm * 64;
    const int b = mwave >> 10, s_wb = mwave & 1023;
    if (which == 2) {
      // V: transpose 64x64 wave-tile in this wave's 8KB LDS slice
      unsigned short* tl = (unsigned short*)&sM[0][0] + (size_t)wid * (64 * 64);
#pragma unroll
      for (int i2 = 0; i2 < 4; ++i2)
#pragma unroll
        for (int nf = 0; nf < 4; ++nf) {
          const int d = nf * 16 + r;
          const float bias = bias2[hn * 64 + d];
          s16x4 o;
#pragma unroll
          for (int j = 0; j < 4; ++j) o[j] = (short)f2bf(acc[i2][nf][j] + bias);
          *(s16x4*)&tl[d * 64 + i2 * 16 + 4 * g] = o;
        }
      unsigned short* vout = obf + (size_t)2 * (M_TOTAL * DM) +
                             ((size_t)(b * NH + hn) * DH) * SEQ + s_wb;
#pragma unroll
      for (int p2 = 0; p2 < 16; ++p2) {
        const int d = p2 * 4 + g;
        const s16x4 v = *(const s16x4*)&tl[d * 64 + 4 * r];
        *(s16x4*)(vout + (size_t)d * SEQ + 4 * r) = v;
      }
    } else {
#pragma unroll
      for (int i2 = 0; i2 < 4; ++i2)
#pragma unroll
        for (int nf = 0; nf < 4; ++nf) {
          const int d = nf * 16 + r;
          const float bias = (which == 0) ? bias0[hn * 64 + d] : bias1[hn * 64 + d];
          const int s_base = s_wb + i2 * 16 + 4 * g;
#pragma unroll
          for (int j = 0; j < 4; ++j) {
            float v = acc[i2][nf][j] + bias;
            if (which == 0) v *= 0.1803368801f;  // 1/8 * log2(e): exp2-domain scores
            obf[(size_t)which * (M_TOTAL * DM) +
                (((size_t)(b * NH + hn) * SEQ + (s_base + j)) * DH + d)] = f2bf(v);
          }
        }
    }
  } else {
#pragma unroll
    for (int i2 = 0; i2 < 4; ++i2)
#pragma unroll
      for (int j = 0; j < 4; ++j) {
        const int m = m0 + wm * 64 + i2 * 16 + 4 * g + j;
#pragma unroll
        for (int nf = 0; nf < 4; ++nf) {
          const int n = n0 + wn * 64 + nf * 16 + r;
          epi_store<MODE>(m, n, acc[i2][nf][j], Nout, obf, of, res, bias0);
        }
      }
  }
}

// ---------------- flash attention (swapped-QK, swizzled LDS, prefetch) ------
// Q pre-scaled by (1/8)*log2(e) -> softmax in exp2 domain (p = 2^(s-m)).
// V already transposed: VT[bh][d][s] at QKV slice 2.
// defer-max (T13): skip O-rescale when per-tile max growth <= 8 (log2 units).
__global__ __launch_bounds__(256)
void attn_kernel(const unsigned short* __restrict__ QKV,
                 unsigned short* __restrict__ O) {
  const unsigned short* Qg = QKV;
  const unsigned short* Kg = QKV + (size_t)M_TOTAL * DM;
  const unsigned short* VTg = QKV + 2 * (size_t)M_TOTAL * DM;
  const int bh = blockIdx.y;
  const int q0 = blockIdx.x * 64;
  const int t = threadIdx.x, w = t >> 6, lane = t & 63;
  const int g = lane >> 4, r = lane & 15;
  const unsigned short* Qb = Qg + (size_t)bh * SEQ * DH;
  const unsigned short* Kb = Kg + (size_t)bh * SEQ * DH;
  const unsigned short* VTb = VTg + (size_t)bh * DH * SEQ;

  __shared__ __attribute__((aligned(16))) unsigned short sK[2][64 * 64];
  __shared__ __attribute__((aligned(16))) unsigned short sV[2][64 * 64];

  s16x8 qf[2];
  {
    const unsigned short* qrow = Qb + (size_t)(q0 + w * 16 + r) * DH;
    qf[0] = *(const s16x8*)(qrow + g * 8);
    qf[1] = *(const s16x8*)(qrow + 32 + g * 8);
  }

  f32x4 oacc[4];
#pragma unroll
  for (int i = 0; i < 4; ++i) oacc[i] = (f32x4){0.f, 0.f, 0.f, 0.f};
  float mrun = -1e30f, lrun = 0.f;

  auto stage = [&](int buf, int kt) {
#pragma unroll
    for (int s2 = 0; s2 < 2; ++s2) {
      const int f = s2 * 256 + t;
      const int row = f >> 3, u = (f & 7) ^ (row & 7);
      gload16(Kb + (size_t)(kt * 64 + row) * DH + u * 8, &sK[buf][f * 8]);
      gload16(VTb + (size_t)row * SEQ + kt * 64 + u * 8, &sV[buf][f * 8]);
    }
  };

  stage(0, 0);
  __syncthreads();

  for (int kt = 0; kt < SEQ / 64; ++kt) {
    const int cur = kt & 1;
    if (kt < SEQ / 64 - 1) stage(cur ^ 1, kt + 1);

    f32x4 sc[4];
#pragma unroll
    for (int nf = 0; nf < 4; ++nf) {
      sc[nf] = (f32x4){0.f, 0.f, 0.f, 0.f};
      const int rowk = nf * 16 + r;
#pragma unroll
      for (int ks = 0; ks < 2; ++ks) {
        const int u = (4 * ks + g) ^ (rowk & 7);
        const s16x8 kf = *(const s16x8*)&sK[cur][rowk * 64 + u * 8];
        sc[nf] = __builtin_amdgcn_mfma_f32_16x16x32_bf16(kf, qf[ks], sc[nf], 0, 0, 0);
      }
    }

    float pm = -1e30f;
#pragma unroll
    for (int nf = 0; nf < 4; ++nf)
#pragma unroll
      for (int j = 0; j < 4; ++j) pm = fmaxf(pm, sc[nf][j]);
    pm = fmaxf(pm, __shfl_xor(pm, 16, 64));
    pm = fmaxf(pm, __shfl_xor(pm, 32, 64));

    if (!__all(pm - mrun <= 8.0f)) {
      const float mnew = fmaxf(mrun, pm);
      const float alpha = exp2_fast(mrun - mnew);
      mrun = mnew;
      lrun *= alpha;
      float ao[4];
#pragma unroll
      for (int j = 0; j < 4; ++j) ao[j] = __shfl(alpha, 4 * g + j, 64);
#pragma unroll
      for (int nf2 = 0; nf2 < 4; ++nf2)
#pragma unroll
        for (int j = 0; j < 4; ++j) oacc[nf2][j] *= ao[j];
    }

    float p[4][4];
    float ps = 0.f;
#pragma unroll
    for (int nf = 0; nf < 4; ++nf)
#pragma unroll
      for (int j = 0; j < 4; ++j) {
        p[nf][j] = exp2_fast(sc[nf][j] - mrun);   // bounded by 2^8
        ps += p[nf][j];
      }
    ps += __shfl_xor(ps, 16, 64);
    ps += __shfl_xor(ps, 32, 64);
    lrun += ps;

    unsigned int pk[4][2];
#pragma unroll
    for (int nf = 0; nf < 4; ++nf)
#pragma unroll
      for (int jp = 0; jp < 2; ++jp)
        pk[nf][jp] = cvt_pk_bf16(p[nf][2 * jp], p[nf][2 * jp + 1]);

    unsigned int pa32[2][4];
#pragma unroll
    for (int ks = 0; ks < 2; ++ks)
#pragma unroll
      for (int q2 = 0; q2 < 4; ++q2) {
        const int src = r + 32 * (g & 1) + 16 * (q2 >> 1);
        const unsigned int a = (unsigned int)__shfl((int)pk[2 * ks][q2 & 1], src, 64);
        const unsigned int b = (unsigned int)__shfl((int)pk[2 * ks + 1][q2 & 1], src, 64);
        pa32[ks][q2] = (g >> 1) ? b : a;
      }
    s16x8 pa[2];
#pragma unroll
    for (int ks = 0; ks < 2; ++ks) {
      u32x4 pw;
      pw[0] = pa32[ks][0]; pw[1] = pa32[ks][1];
      pw[2] = pa32[ks][2]; pw[3] = pa32[ks][3];
      pa[ks] = __builtin_bit_cast(s16x8, pw);
    }

#pragma unroll
    for (int nf2 = 0; nf2 < 4; ++nf2) {
      const int rowd = nf2 * 16 + r;
#pragma unroll
      for (int ks = 0; ks < 2; ++ks) {
        const int u = (4 * ks + g) ^ (rowd & 7);
        const s16x8 vb = *(const s16x8*)&sV[cur][rowd * 64 + u * 8];
        oacc[nf2] = __builtin_amdgcn_mfma_f32_16x16x32_bf16(pa[ks], vb, oacc[nf2], 0, 0, 0);
      }
    }
    __syncthreads();
  }

  const int b = bh >> 4, h = bh & 15;
  const float linv = 1.f / lrun;
#pragma unroll
  for (int j = 0; j < 4; ++j) {
    const float lo = __shfl(linv, 4 * g + j, 64);
    const int q = q0 + w * 16 + 4 * g + j;
    const size_t orow = ((size_t)(b * SEQ + q)) * DM + h * DH;
#pragma unroll
    for (int nf2 = 0; nf2 < 4; ++nf2)
      O[orow + nf2 * 16 + r] = f2bf(oacc[nf2][j] * lo);
  }
}

// ---------------------------------------------------------------------------
extern "C" void kernel_launch(void* const* d_in, const int* in_sizes, int n_in,
                              void* d_out, int out_size, void* d_ws, size_t ws_size,
                              hipStream_t stream) {
  const float* x   = (const float*)d_in[0];
  const float* al1 = (const float*)d_in[1];
  const float* be1 = (const float*)d_in[2];
  const float* al2 = (const float*)d_in[3];
  const float* be2 = (const float*)d_in[4];
  const float* wq  = (const float*)d_in[5];
  const float* bq  = (const float*)d_in[6];
  const float* wk  = (const float*)d_in[7];
  const float* bk  = (const float*)d_in[8];
  const float* wv  = (const float*)d_in[9];
  const float* bv  = (const float*)d_in[10];
  const float* wo  = (const float*)d_in[11];
  const float* bo  = (const float*)d_in[12];
  const float* w1  = (const float*)d_in[13];
  const float* b1  = (const float*)d_in[14];
  const float* w2  = (const float*)d_in[15];
  const float* b2  = (const float*)d_in[16];
  float* dout = (float*)d_out;

  unsigned short* ws = (unsigned short*)d_ws;
  size_t off = 0;
  auto alloc = [&](size_t n) { unsigned short* p = ws + off; off += n; return p; };
  unsigned short* WTqkv = alloc((size_t)3072 * 1024);
  unsigned short* WTo   = alloc((size_t)1024 * 1024);
  unsigned short* WT1   = alloc((size_t)4096 * 1024);
  unsigned short* WT2   = alloc((size_t)1024 * 4096);
  unsigned short* xn    = alloc((size_t)M_TOTAL * DM);
  unsigned short* QKVb  = alloc((size_t)3 * M_TOTAL * DM);  // Q, K, V^T slices
  unsigned short* attn  = alloc((size_t)M_TOTAL * DM);
  unsigned short* h1    = alloc((size_t)M_TOTAL * HID);
  (void)ws_size; (void)in_sizes; (void)n_in; (void)out_size;

  // all 6 weight transposes in one launch
  tcast_all<<<12288, dim3(32, 8), 0, stream>>>(wq, wk, wv, wo, w1, w2,
                                               WTqkv, WTo, WT1, WT2);

  // LN1: x -> xn (bf16)
  ln_kernel<<<M_TOTAL, 256, 0, stream>>>(x, al1, be1, xn);
  // QKV projection: 1536 wgs -> single-buffered 4-blocks/CU kernel
  gemms<0><<<dim3(24, 64), 256, 0, stream>>>(xn, WTqkv, 1024, 3072,
                                             QKVb, nullptr, nullptr, bq, bk, bv);
  // attention (reads Q, K, V^T from QKVb)
  attn_kernel<<<dim3(16, 128), 256, 0, stream>>>(QKVb, attn);
  // O projection + residual: 512 wgs -> double-buffered kernel
  gemmk<1><<<dim3(8, 64), 256, 0, stream>>>(attn, WTo, 1024, 1024,
                                            nullptr, dout, x, bo, nullptr, nullptr);
  // LN2: dout -> xn (bf16)
  ln_kernel<<<M_TOTAL, 256, 0, stream>>>(dout, al2, be2, xn);
  // MLP1 + GELU: 2048 wgs -> single-buffered 4-blocks/CU kernel
  gemms<2><<<dim3(32, 64), 256, 0, stream>>>(xn, WT1, 1024, 4096,
                                             h1, nullptr, nullptr, b1, nullptr, nullptr);
  // MLP2 + residual: 512 wgs -> double-buffered kernel
  gemmk<1><<<dim3(8, 64), 256, 0, stream>>>(h1, WT2, 4096, 1024,
                                            nullptr, dout, dout, b2, nullptr, nullptr);
}

// Round 16
// 382.744 us; speedup vs baseline: 1.0829x; 1.0336x over previous
//
#include <hip/hip_runtime.h>
#include <stdint.h>

typedef float f32x4 __attribute__((ext_vector_type(4)));
typedef short s16x8 __attribute__((ext_vector_type(8)));
typedef short s16x4 __attribute__((ext_vector_type(4)));
typedef unsigned int u32x4 __attribute__((ext_vector_type(4)));

#define M_TOTAL 8192
#define DM 1024
#define HID 4096
#define SEQ 1024
#define NH 16
#define DH 64

#define BAR() __builtin_amdgcn_s_barrier()
#define VMCNT8() do { asm volatile("s_waitcnt vmcnt(8)" ::: "memory"); __builtin_amdgcn_sched_barrier(0); } while (0)
#define VMCNT0() do { asm volatile("s_waitcnt vmcnt(0)" ::: "memory"); __builtin_amdgcn_sched_barrier(0); } while (0)
#define MFMA16 __builtin_amdgcn_mfma_f32_16x16x32_bf16

__device__ __forceinline__ unsigned short f2bf(float f) {
  unsigned int u = __float_as_uint(f);
  u = (u + 0x7fffu + ((u >> 16) & 1u)) >> 16;
  return (unsigned short)u;
}

// packed f32x2 -> bf16x2 in one instruction (gfx950)
__device__ __forceinline__ unsigned int cvt_pk_bf16(float lo, float hi) {
  unsigned int r;
  asm("v_cvt_pk_bf16_f32 %0, %1, %2" : "=v"(r) : "v"(lo), "v"(hi));
  return r;
}

// raw v_exp_f32: D = 2^S0
__device__ __forceinline__ float exp2_fast(float x) {
  float r;
  asm("v_exp_f32 %0, %1" : "=v"(r) : "v"(x));
  return r;
}

__device__ __forceinline__ void gload16(const void* g, void* l) {
  __builtin_amdgcn_global_load_lds((__attribute__((address_space(1))) void*)g,
                                   (__attribute__((address_space(3))) void*)l,
                                   16, 0, 0);
}

// fast erf (Abramowitz-Stegun 7.1.26, |err| <= 1.5e-7)
__device__ __forceinline__ float erf_fast(float z) {
  const float az = fabsf(z);
  const float tt = 1.0f / fmaf(0.3275911f, az, 1.0f);
  float poly = fmaf(1.061405429f, tt, -1.453152027f);
  poly = fmaf(poly, tt, 1.421413741f);
  poly = fmaf(poly, tt, -0.284496736f);
  poly = fmaf(poly, tt, 0.254829592f);
  poly *= tt;
  const float e = __expf(-az * az);
  const float r = 1.0f - poly * e;
  return (z < 0.f) ? -r : r;
}

// ------- batched transpose+cast f32 -> bf16 for all 6 weight matrices -------
__global__ void tcast_all(const float* __restrict__ wq, const float* __restrict__ wk,
                          const float* __restrict__ wv, const float* __restrict__ wo,
                          const float* __restrict__ w1, const float* __restrict__ w2,
                          unsigned short* __restrict__ WTqkv, unsigned short* __restrict__ WTo,
                          unsigned short* __restrict__ WT1, unsigned short* __restrict__ WT2) {
  __shared__ float tile[32][33];
  const int b = blockIdx.x;
  const float* W;
  unsigned short* WT;
  int K, N, bn, bk;
  if (b < 4096) {
    const int j = b >> 10, t2 = b & 1023;
    K = 1024; N = 1024;
    bn = t2 & 31; bk = t2 >> 5;
    W = (j == 0) ? wq : (j == 1) ? wk : (j == 2) ? wv : wo;
    WT = (j < 3) ? (WTqkv + (size_t)j * 1024 * 1024) : WTo;
  } else if (b < 8192) {
    const int t2 = b - 4096;
    K = 1024; N = 4096;
    bn = t2 & 127; bk = t2 >> 7;
    W = w1; WT = WT1;
  } else {
    const int t2 = b - 8192;
    K = 4096; N = 1024;
    bn = t2 & 31; bk = t2 >> 5;
    W = w2; WT = WT2;
  }
  const int tx = threadIdx.x, ty = threadIdx.y;  // 32 x 8
#pragma unroll
  for (int i = 0; i < 32; i += 8)
    tile[ty + i][tx] = W[(size_t)(bk * 32 + ty + i) * N + bn * 32 + tx];
  __syncthreads();
#pragma unroll
  for (int i = 0; i < 32; i += 8)
    WT[(size_t)(bn * 32 + ty + i) * K + bk * 32 + tx] = f2bf(tile[tx][ty + i]);
}

// ---------------- LayerNorm (ddof=1) f32 in -> bf16 out ---------------------
__global__ __launch_bounds__(256)
void ln_kernel(const float* __restrict__ x, const float* __restrict__ alpha,
               const float* __restrict__ beta, unsigned short* __restrict__ out) {
  const int row = blockIdx.x;
  const int t = threadIdx.x;
  const int w = t >> 6, lane = t & 63;
  const float4 v = ((const float4*)(x + (size_t)row * DM))[t];

  float s = v.x + v.y + v.z + v.w;
#pragma unroll
  for (int off = 32; off; off >>= 1) s += __shfl_xor(s, off, 64);
  __shared__ float red1[4];
  __shared__ float red2[4];
  if (lane == 0) red1[w] = s;
  __syncthreads();
  const float mu = (red1[0] + red1[1] + red1[2] + red1[3]) * (1.f / 1024.f);

  const float dx = v.x - mu, dy = v.y - mu, dz = v.z - mu, dw = v.w - mu;
  float sq = dx * dx + dy * dy + dz * dz + dw * dw;
#pragma unroll
  for (int off = 32; off; off >>= 1) sq += __shfl_xor(sq, off, 64);
  if (lane == 0) red2[w] = sq;
  __syncthreads();
  const float var = (red2[0] + red2[1] + red2[2] + red2[3]) * (1.f / 1023.f);
  const float rstd = rsqrtf(var + 1e-6f);

  const float4 a = ((const float4*)alpha)[t];
  const float4 b = ((const float4*)beta)[t];
  const float o0 = dx * rstd * a.x + b.x;
  const float o1 = dy * rstd * a.y + b.y;
  const float o2 = dz * rstd * a.z + b.z;
  const float o3 = dw * rstd * a.w + b.w;
  uint2 ov;
  ov.x = cvt_pk_bf16(o0, o1);
  ov.y = cvt_pk_bf16(o2, o3);
  *(uint2*)(out + (size_t)row * DM + 4 * t) = ov;
}

// ---------------- shared epilogue (MODE 1 / MODE 2) -------------------------
template <int MODE>
__device__ __forceinline__ void epi_store(int m, int n, float v, int Nout,
                                          unsigned short* __restrict__ obf, float* of,
                                          const float* res,
                                          const float* __restrict__ bias0) {
  if (MODE == 1) {
    v += bias0[n] + res[(size_t)m * Nout + n];
    of[(size_t)m * Nout + n] = v;
  } else {
    v += bias0[n];
    const float gv = 0.5f * v * (1.0f + erf_fast(v * 0.70710678118654752f));
    obf[(size_t)m * Nout + n] = f2bf(gv);
  }
}

// ---- XCD supertile mapping for WIDE-N grids (gemms): gridDim.y == 64 -------
__device__ __forceinline__ void supertile_map(int& m0, int& n0) {
  const int L = blockIdx.y * gridDim.x + blockIdx.x;
  const int nwg = gridDim.x * gridDim.y;
  const int chunk = nwg >> 3;
  const int ncols = chunk >> 6;
  const int denom = ncols << 3;
  const int xcd = L & 7, li = L >> 3;
  const int sst = li / denom, wst = li % denom;
  const int by = sst * 8 + (wst & 7);
  const int bx = xcd * ncols + (wst >> 3);
  m0 = by * 128; n0 = bx * 128;
}

// ---------------- 128x128x64 GEMM, DOUBLE-buffered (r8) ---------------------
// For tall-skinny grids 8x64 (O-proj, MLP2). 64KB LDS, 2 blocks/CU.
// M-sliced XCD map: each XCD owns 8 contiguous block-rows x all 8 N-cols
// (bx-fastest) -> A-panel read by exactly one XCD; B (<=8MB) L3-resident.
template <int MODE>
__global__ __launch_bounds__(256, 2)
void gemmk(const unsigned short* __restrict__ A, const unsigned short* __restrict__ B,
           int K, int Nout,
           unsigned short* __restrict__ obf, float* of, const float* res,
           const float* __restrict__ bias0, const float* __restrict__ bias1,
           const float* __restrict__ bias2) {
  __shared__ __attribute__((aligned(16))) unsigned short sA[2][128 * 64];
  __shared__ __attribute__((aligned(16))) unsigned short sB[2][128 * 64];
  const int t = threadIdx.x;
  const int lane = t & 63, wid = t >> 6;
  const int g = lane >> 4, r = lane & 15;
  const int wm = wid >> 1, wn = wid & 1;

  // M-sliced XCD map (requires gridDim.x == 8, gridDim.y == 64)
  const int L = blockIdx.y * gridDim.x + blockIdx.x;
  const int xcd = L & 7, li = L >> 3;      // li in [0,64)
  const int bx = li & 7;                   // fastest: A-panel L2 reuse
  const int by = xcd * 8 + (li >> 3);      // XCD owns 8 contiguous block-rows
  const int m0 = by * 128, n0 = bx * 128;

  const unsigned short* Ab = A + (size_t)m0 * K;
  const unsigned short* Bb = B + (size_t)n0 * K;

  const int rb = r & 7;
  const int slot0 = (g ^ rb) * 16;
  const int slot1 = ((4 + g) ^ rb) * 16;

  f32x4 acc[4][4];
#pragma unroll
  for (int i2 = 0; i2 < 4; ++i2)
#pragma unroll
    for (int j = 0; j < 4; ++j) acc[i2][j] = (f32x4){0.f, 0.f, 0.f, 0.f};

  auto stage = [&](int buf, int kt) {
#pragma unroll
    for (int s2 = 0; s2 < 4; ++s2) {
      const int f = s2 * 256 + t;
      const int row = f >> 3, c = f & 7;
      const int u = c ^ (row & 7);
      gload16(Ab + (size_t)row * K + kt * 64 + u * 8, &sA[buf][(size_t)row * 64 + c * 8]);
      gload16(Bb + (size_t)row * K + kt * 64 + u * 8, &sB[buf][(size_t)row * 64 + c * 8]);
    }
  };

  const int NT = K >> 6;
  stage(0, 0);
  stage(1, (NT > 1) ? 1 : 0);
  VMCNT8();
  BAR();

  for (int tt = 0; tt < NT; ++tt) {
    const int cur = tt & 1;
    const char* sAc = (const char*)&sA[cur][0];
    const char* sBc = (const char*)&sB[cur][0];

    s16x8 av[4][2], bv[4][2];
#pragma unroll
    for (int i2 = 0; i2 < 4; ++i2) {
      const int rbyte = (wm * 64 + i2 * 16 + r) * 128;
      av[i2][0] = *(const s16x8*)(sAc + rbyte + slot0);
      av[i2][1] = *(const s16x8*)(sAc + rbyte + slot1);
    }
#pragma unroll
    for (int n = 0; n < 4; ++n) {
      const int rbyte = (wn * 64 + n * 16 + r) * 128;
      bv[n][0] = *(const s16x8*)(sBc + rbyte + slot0);
      bv[n][1] = *(const s16x8*)(sBc + rbyte + slot1);
    }
#pragma unroll
    for (int i2 = 0; i2 < 4; ++i2)
#pragma unroll
      for (int n = 0; n < 4; ++n) {
        acc[i2][n] = MFMA16(av[i2][0], bv[n][0], acc[i2][n], 0, 0, 0);
        acc[i2][n] = MFMA16(av[i2][1], bv[n][1], acc[i2][n], 0, 0, 0);
      }

    BAR();
    const int tp2 = (tt + 2 < NT) ? tt + 2 : NT - 1;
    stage(cur, tp2);
    VMCNT8();
    BAR();
  }

  VMCNT0();

#pragma unroll
  for (int i2 = 0; i2 < 4; ++i2)
#pragma unroll
    for (int j = 0; j < 4; ++j) {
      const int m = m0 + wm * 64 + i2 * 16 + 4 * g + j;
#pragma unroll
      for (int nf = 0; nf < 4; ++nf) {
        const int n = n0 + wn * 64 + nf * 16 + r;
        epi_store<MODE>(m, n, acc[i2][nf][j], Nout, obf, of, res, bias0);
      }
    }
}

// ---------------- 128x128x64 GEMM, SINGLE-buffered, 4 blocks/CU -------------
// 32KB LDS; TLP (3 partner blocks) covers the per-tile vmcnt(0) latency.
// For grids >= 1024 wgs (QKV MODE 0, MLP1 MODE 2).
template <int MODE>
__global__ __launch_bounds__(256, 4)
void gemms(const unsigned short* __restrict__ A, const unsigned short* __restrict__ B,
           int K, int Nout,
           unsigned short* __restrict__ obf, float* of, const float* res,
           const float* __restrict__ bias0, const float* __restrict__ bias1,
           const float* __restrict__ bias2) {
  __shared__ __attribute__((aligned(16))) unsigned short sM[2][128 * 64]; // [0]=A [1]=B
  const int t = threadIdx.x;
  const int lane = t & 63, wid = t >> 6;
  const int g = lane >> 4, r = lane & 15;
  const int wm = wid >> 1, wn = wid & 1;

  int m0, n0;
  supertile_map(m0, n0);

  const unsigned short* Ab = A + (size_t)m0 * K;
  const unsigned short* Bb = B + (size_t)n0 * K;

  const int rb = r & 7;
  const int slot0 = (g ^ rb) * 16;
  const int slot1 = ((4 + g) ^ rb) * 16;

  f32x4 acc[4][4];
#pragma unroll
  for (int i2 = 0; i2 < 4; ++i2)
#pragma unroll
    for (int j = 0; j < 4; ++j) acc[i2][j] = (f32x4){0.f, 0.f, 0.f, 0.f};

  auto stage = [&](int kt) {
#pragma unroll
    for (int s2 = 0; s2 < 4; ++s2) {
      const int f = s2 * 256 + t;
      const int row = f >> 3, c = f & 7;
      const int u = c ^ (row & 7);
      gload16(Ab + (size_t)row * K + kt * 64 + u * 8, &sM[0][(size_t)row * 64 + c * 8]);
      gload16(Bb + (size_t)row * K + kt * 64 + u * 8, &sM[1][(size_t)row * 64 + c * 8]);
    }
  };

  const int NT = K >> 6;
  stage(0);
  VMCNT0();
  BAR();

  for (int tt = 0; tt < NT; ++tt) {
    const char* sAc = (const char*)&sM[0][0];
    const char* sBc = (const char*)&sM[1][0];

    s16x8 av[4][2], bv[4][2];
#pragma unroll
    for (int i2 = 0; i2 < 4; ++i2) {
      const int rbyte = (wm * 64 + i2 * 16 + r) * 128;
      av[i2][0] = *(const s16x8*)(sAc + rbyte + slot0);
      av[i2][1] = *(const s16x8*)(sAc + rbyte + slot1);
    }
#pragma unroll
    for (int n = 0; n < 4; ++n) {
      const int rbyte = (wn * 64 + n * 16 + r) * 128;
      bv[n][0] = *(const s16x8*)(sBc + rbyte + slot0);
      bv[n][1] = *(const s16x8*)(sBc + rbyte + slot1);
    }
#pragma unroll
    for (int i2 = 0; i2 < 4; ++i2)
#pragma unroll
      for (int n = 0; n < 4; ++n) {
        acc[i2][n] = MFMA16(av[i2][0], bv[n][0], acc[i2][n], 0, 0, 0);
        acc[i2][n] = MFMA16(av[i2][1], bv[n][1], acc[i2][n], 0, 0, 0);
      }

    BAR();                                    // all waves done reading sM
    stage((tt + 1 < NT) ? tt + 1 : tt);       // unconditional clamped re-stage
    VMCNT0();                                 // own DMAs landed
    BAR();                                    // all waves' DMAs landed
  }
  // loop exit: VMCNT0+BAR already executed -> LDS reusable, DMA quiet

  if (MODE == 0) {
    const int which = n0 >> 10;
    const int hn = ((n0 & 1023) + wn * 64) >> 6;
    const int mwave = m0 + wm * 64;
    const int b = mwave >> 10, s_wb = mwave & 1023;
    if (which == 2) {
      // V: transpose 64x64 wave-tile in this wave's 8KB LDS slice
      unsigned short* tl = (unsigned short*)&sM[0][0] + (size_t)wid * (64 * 64);
#pragma unroll
      for (int i2 = 0; i2 < 4; ++i2)
#pragma unroll
        for (int nf = 0; nf < 4; ++nf) {
          const int d = nf * 16 + r;
          const float bias = bias2[hn * 64 + d];
          s16x4 o;
#pragma unroll
          for (int j = 0; j < 4; ++j) o[j] = (short)f2bf(acc[i2][nf][j] + bias);
          *(s16x4*)&tl[d * 64 + i2 * 16 + 4 * g] = o;
        }
      unsigned short* vout = obf + (size_t)2 * (M_TOTAL * DM) +
                             ((size_t)(b * NH + hn) * DH) * SEQ + s_wb;
#pragma unroll
      for (int p2 = 0; p2 < 16; ++p2) {
        const int d = p2 * 4 + g;
        const s16x4 v = *(const s16x4*)&tl[d * 64 + 4 * r];
        *(s16x4*)(vout + (size_t)d * SEQ + 4 * r) = v;
      }
    } else {
#pragma unroll
      for (int i2 = 0; i2 < 4; ++i2)
#pragma unroll
        for (int nf = 0; nf < 4; ++nf) {
          const int d = nf * 16 + r;
          const float bias = (which == 0) ? bias0[hn * 64 + d] : bias1[hn * 64 + d];
          const int s_base = s_wb + i2 * 16 + 4 * g;
#pragma unroll
          for (int j = 0; j < 4; ++j) {
            float v = acc[i2][nf][j] + bias;
            if (which == 0) v *= 0.1803368801f;  // 1/8 * log2(e): exp2-domain scores
            obf[(size_t)which * (M_TOTAL * DM) +
                (((size_t)(b * NH + hn) * SEQ + (s_base + j)) * DH + d)] = f2bf(v);
          }
        }
    }
  } else {
#pragma unroll
    for (int i2 = 0; i2 < 4; ++i2)
#pragma unroll
      for (int j = 0; j < 4; ++j) {
        const int m = m0 + wm * 64 + i2 * 16 + 4 * g + j;
#pragma unroll
        for (int nf = 0; nf < 4; ++nf) {
          const int n = n0 + wn * 64 + nf * 16 + r;
          epi_store<MODE>(m, n, acc[i2][nf][j], Nout, obf, of, res, bias0);
        }
      }
  }
}

// ---------------- flash attention (swapped-QK, swizzled LDS, prefetch) ------
// Q pre-scaled by (1/8)*log2(e) -> softmax in exp2 domain (p = 2^(s-m)).
// V already transposed: VT[bh][d][s] at QKV slice 2.
// defer-max (T13): skip O-rescale when per-tile max growth <= 8 (log2 units).
__global__ __launch_bounds__(256)
void attn_kernel(const unsigned short* __restrict__ QKV,
                 unsigned short* __restrict__ O) {
  const unsigned short* Qg = QKV;
  const unsigned short* Kg = QKV + (size_t)M_TOTAL * DM;
  const unsigned short* VTg = QKV + 2 * (size_t)M_TOTAL * DM;
  const int bh = blockIdx.y;
  const int q0 = blockIdx.x * 64;
  const int t = threadIdx.x, w = t >> 6, lane = t & 63;
  const int g = lane >> 4, r = lane & 15;
  const unsigned short* Qb = Qg + (size_t)bh * SEQ * DH;
  const unsigned short* Kb = Kg + (size_t)bh * SEQ * DH;
  const unsigned short* VTb = VTg + (size_t)bh * DH * SEQ;

  __shared__ __attribute__((aligned(16))) unsigned short sK[2][64 * 64];
  __shared__ __attribute__((aligned(16))) unsigned short sV[2][64 * 64];

  s16x8 qf[2];
  {
    const unsigned short* qrow = Qb + (size_t)(q0 + w * 16 + r) * DH;
    qf[0] = *(const s16x8*)(qrow + g * 8);
    qf[1] = *(const s16x8*)(qrow + 32 + g * 8);
  }

  f32x4 oacc[4];
#pragma unroll
  for (int i = 0; i < 4; ++i) oacc[i] = (f32x4){0.f, 0.f, 0.f, 0.f};
  float mrun = -1e30f, lrun = 0.f;

  auto stage = [&](int buf, int kt) {
#pragma unroll
    for (int s2 = 0; s2 < 2; ++s2) {
      const int f = s2 * 256 + t;
      const int row = f >> 3, u = (f & 7) ^ (row & 7);
      gload16(Kb + (size_t)(kt * 64 + row) * DH + u * 8, &sK[buf][f * 8]);
      gload16(VTb + (size_t)row * SEQ + kt * 64 + u * 8, &sV[buf][f * 8]);
    }
  };

  stage(0, 0);
  __syncthreads();

  for (int kt = 0; kt < SEQ / 64; ++kt) {
    const int cur = kt & 1;
    if (kt < SEQ / 64 - 1) stage(cur ^ 1, kt + 1);

    f32x4 sc[4];
#pragma unroll
    for (int nf = 0; nf < 4; ++nf) {
      sc[nf] = (f32x4){0.f, 0.f, 0.f, 0.f};
      const int rowk = nf * 16 + r;
#pragma unroll
      for (int ks = 0; ks < 2; ++ks) {
        const int u = (4 * ks + g) ^ (rowk & 7);
        const s16x8 kf = *(const s16x8*)&sK[cur][rowk * 64 + u * 8];
        sc[nf] = __builtin_amdgcn_mfma_f32_16x16x32_bf16(kf, qf[ks], sc[nf], 0, 0, 0);
      }
    }

    float pm = -1e30f;
#pragma unroll
    for (int nf = 0; nf < 4; ++nf)
#pragma unroll
      for (int j = 0; j < 4; ++j) pm = fmaxf(pm, sc[nf][j]);
    pm = fmaxf(pm, __shfl_xor(pm, 16, 64));
    pm = fmaxf(pm, __shfl_xor(pm, 32, 64));

    if (!__all(pm - mrun <= 8.0f)) {
      const float mnew = fmaxf(mrun, pm);
      const float alpha = exp2_fast(mrun - mnew);
      mrun = mnew;
      lrun *= alpha;
      float ao[4];
#pragma unroll
      for (int j = 0; j < 4; ++j) ao[j] = __shfl(alpha, 4 * g + j, 64);
#pragma unroll
      for (int nf2 = 0; nf2 < 4; ++nf2)
#pragma unroll
        for (int j = 0; j < 4; ++j) oacc[nf2][j] *= ao[j];
    }

    float p[4][4];
    float ps = 0.f;
#pragma unroll
    for (int nf = 0; nf < 4; ++nf)
#pragma unroll
      for (int j = 0; j < 4; ++j) {
        p[nf][j] = exp2_fast(sc[nf][j] - mrun);   // bounded by 2^8
        ps += p[nf][j];
      }
    ps += __shfl_xor(ps, 16, 64);
    ps += __shfl_xor(ps, 32, 64);
    lrun += ps;

    unsigned int pk[4][2];
#pragma unroll
    for (int nf = 0; nf < 4; ++nf)
#pragma unroll
      for (int jp = 0; jp < 2; ++jp)
        pk[nf][jp] = cvt_pk_bf16(p[nf][2 * jp], p[nf][2 * jp + 1]);

    unsigned int pa32[2][4];
#pragma unroll
    for (int ks = 0; ks < 2; ++ks)
#pragma unroll
      for (int q2 = 0; q2 < 4; ++q2) {
        const int src = r + 32 * (g & 1) + 16 * (q2 >> 1);
        const unsigned int a = (unsigned int)__shfl((int)pk[2 * ks][q2 & 1], src, 64);
        const unsigned int b = (unsigned int)__shfl((int)pk[2 * ks + 1][q2 & 1], src, 64);
        pa32[ks][q2] = (g >> 1) ? b : a;
      }
    s16x8 pa[2];
#pragma unroll
    for (int ks = 0; ks < 2; ++ks) {
      u32x4 pw;
      pw[0] = pa32[ks][0]; pw[1] = pa32[ks][1];
      pw[2] = pa32[ks][2]; pw[3] = pa32[ks][3];
      pa[ks] = __builtin_bit_cast(s16x8, pw);
    }

#pragma unroll
    for (int nf2 = 0; nf2 < 4; ++nf2) {
      const int rowd = nf2 * 16 + r;
#pragma unroll
      for (int ks = 0; ks < 2; ++ks) {
        const int u = (4 * ks + g) ^ (rowd & 7);
        const s16x8 vb = *(const s16x8*)&sV[cur][rowd * 64 + u * 8];
        oacc[nf2] = __builtin_amdgcn_mfma_f32_16x16x32_bf16(pa[ks], vb, oacc[nf2], 0, 0, 0);
      }
    }
    __syncthreads();
  }

  const int b = bh >> 4, h = bh & 15;
  const float linv = 1.f / lrun;
#pragma unroll
  for (int j = 0; j < 4; ++j) {
    const float lo = __shfl(linv, 4 * g + j, 64);
    const int q = q0 + w * 16 + 4 * g + j;
    const size_t orow = ((size_t)(b * SEQ + q)) * DM + h * DH;
#pragma unroll
    for (int nf2 = 0; nf2 < 4; ++nf2)
      O[orow + nf2 * 16 + r] = f2bf(oacc[nf2][j] * lo);
  }
}

// ---------------------------------------------------------------------------
extern "C" void kernel_launch(void* const* d_in, const int* in_sizes, int n_in,
                              void* d_out, int out_size, void* d_ws, size_t ws_size,
                              hipStream_t stream) {
  const float* x   = (const float*)d_in[0];
  const float* al1 = (const float*)d_in[1];
  const float* be1 = (const float*)d_in[2];
  const float* al2 = (const float*)d_in[3];
  const float* be2 = (const float*)d_in[4];
  const float* wq  = (const float*)d_in[5];
  const float* bq  = (const float*)d_in[6];
  const float* wk  = (const float*)d_in[7];
  const float* bk  = (const float*)d_in[8];
  const float* wv  = (const float*)d_in[9];
  const float* bv  = (const float*)d_in[10];
  const float* wo  = (const float*)d_in[11];
  const float* bo  = (const float*)d_in[12];
  const float* w1  = (const float*)d_in[13];
  const float* b1  = (const float*)d_in[14];
  const float* w2  = (const float*)d_in[15];
  const float* b2  = (const float*)d_in[16];
  float* dout = (float*)d_out;

  unsigned short* ws = (unsigned short*)d_ws;
  size_t off = 0;
  auto alloc = [&](size_t n) { unsigned short* p = ws + off; off += n; return p; };
  unsigned short* WTqkv = alloc((size_t)3072 * 1024);
  unsigned short* WTo   = alloc((size_t)1024 * 1024);
  unsigned short* WT1   = alloc((size_t)4096 * 1024);
  unsigned short* WT2   = alloc((size_t)1024 * 4096);
  unsigned short* xn    = alloc((size_t)M_TOTAL * DM);
  unsigned short* QKVb  = alloc((size_t)3 * M_TOTAL * DM);  // Q, K, V^T slices
  unsigned short* attn  = alloc((size_t)M_TOTAL * DM);
  unsigned short* h1    = alloc((size_t)M_TOTAL * HID);
  (void)ws_size; (void)in_sizes; (void)n_in; (void)out_size;

  // all 6 weight transposes in one launch
  tcast_all<<<12288, dim3(32, 8), 0, stream>>>(wq, wk, wv, wo, w1, w2,
                                               WTqkv, WTo, WT1, WT2);

  // LN1: x -> xn (bf16)
  ln_kernel<<<M_TOTAL, 256, 0, stream>>>(x, al1, be1, xn);
  // QKV projection: 1536 wgs -> single-buffered 4-blocks/CU kernel
  gemms<0><<<dim3(24, 64), 256, 0, stream>>>(xn, WTqkv, 1024, 3072,
                                             QKVb, nullptr, nullptr, bq, bk, bv);
  // attention (reads Q, K, V^T from QKVb)
  attn_kernel<<<dim3(16, 128), 256, 0, stream>>>(QKVb, attn);
  // O projection + residual: 512 wgs -> double-buffered kernel (M-sliced map)
  gemmk<1><<<dim3(8, 64), 256, 0, stream>>>(attn, WTo, 1024, 1024,
                                            nullptr, dout, x, bo, nullptr, nullptr);
  // LN2: dout -> xn (bf16)
  ln_kernel<<<M_TOTAL, 256, 0, stream>>>(dout, al2, be2, xn);
  // MLP1 + GELU: 2048 wgs -> single-buffered 4-blocks/CU kernel
  gemms<2><<<dim3(32, 64), 256, 0, stream>>>(xn, WT1, 1024, 4096,
                                             h1, nullptr, nullptr, b1, nullptr, nullptr);
  // MLP2 + residual: 512 wgs -> double-buffered kernel (M-sliced map)
  gemmk<1><<<dim3(8, 64), 256, 0, stream>>>(h1, WT2, 4096, 1024,
                                            nullptr, dout, dout, b2, nullptr, nullptr);
}

// Round 17
// 370.969 us; speedup vs baseline: 1.1173x; 1.0317x over previous
//
#include <hip/hip_runtime.h>
#include <stdint.h>

typedef float f32x4 __attribute__((ext_vector_type(4)));
typedef short s16x8 __attribute__((ext_vector_type(8)));
typedef short s16x4 __attribute__((ext_vector_type(4)));
typedef unsigned int u32x4 __attribute__((ext_vector_type(4)));

#define M_TOTAL 8192
#define DM 1024
#define HID 4096
#define SEQ 1024
#define NH 16
#define DH 64

#define BAR() __builtin_amdgcn_s_barrier()
#define VMCNT8() do { asm volatile("s_waitcnt vmcnt(8)" ::: "memory"); __builtin_amdgcn_sched_barrier(0); } while (0)
#define VMCNT0() do { asm volatile("s_waitcnt vmcnt(0)" ::: "memory"); __builtin_amdgcn_sched_barrier(0); } while (0)
#define MFMA16 __builtin_amdgcn_mfma_f32_16x16x32_bf16

__device__ __forceinline__ unsigned short f2bf(float f) {
  unsigned int u = __float_as_uint(f);
  u = (u + 0x7fffu + ((u >> 16) & 1u)) >> 16;
  return (unsigned short)u;
}

// packed f32x2 -> bf16x2 in one instruction (gfx950)
__device__ __forceinline__ unsigned int cvt_pk_bf16(float lo, float hi) {
  unsigned int r;
  asm("v_cvt_pk_bf16_f32 %0, %1, %2" : "=v"(r) : "v"(lo), "v"(hi));
  return r;
}

// raw v_exp_f32: D = 2^S0
__device__ __forceinline__ float exp2_fast(float x) {
  float r;
  asm("v_exp_f32 %0, %1" : "=v"(r) : "v"(x));
  return r;
}

__device__ __forceinline__ void gload16(const void* g, void* l) {
  __builtin_amdgcn_global_load_lds((__attribute__((address_space(1))) void*)g,
                                   (__attribute__((address_space(3))) void*)l,
                                   16, 0, 0);
}

// fast erf (Abramowitz-Stegun 7.1.26, |err| <= 1.5e-7)
__device__ __forceinline__ float erf_fast(float z) {
  const float az = fabsf(z);
  const float tt = 1.0f / fmaf(0.3275911f, az, 1.0f);
  float poly = fmaf(1.061405429f, tt, -1.453152027f);
  poly = fmaf(poly, tt, 1.421413741f);
  poly = fmaf(poly, tt, -0.284496736f);
  poly = fmaf(poly, tt, 0.254829592f);
  poly *= tt;
  const float e = __expf(-az * az);
  const float r = 1.0f - poly * e;
  return (z < 0.f) ? -r : r;
}

// ------- batched transpose+cast f32 -> bf16 for all 6 weight matrices -------
__global__ void tcast_all(const float* __restrict__ wq, const float* __restrict__ wk,
                          const float* __restrict__ wv, const float* __restrict__ wo,
                          const float* __restrict__ w1, const float* __restrict__ w2,
                          unsigned short* __restrict__ WTqkv, unsigned short* __restrict__ WTo,
                          unsigned short* __restrict__ WT1, unsigned short* __restrict__ WT2) {
  __shared__ float tile[32][33];
  const int b = blockIdx.x;
  const float* W;
  unsigned short* WT;
  int K, N, bn, bk;
  if (b < 4096) {
    const int j = b >> 10, t2 = b & 1023;
    K = 1024; N = 1024;
    bn = t2 & 31; bk = t2 >> 5;
    W = (j == 0) ? wq : (j == 1) ? wk : (j == 2) ? wv : wo;
    WT = (j < 3) ? (WTqkv + (size_t)j * 1024 * 1024) : WTo;
  } else if (b < 8192) {
    const int t2 = b - 4096;
    K = 1024; N = 4096;
    bn = t2 & 127; bk = t2 >> 7;
    W = w1; WT = WT1;
  } else {
    const int t2 = b - 8192;
    K = 4096; N = 1024;
    bn = t2 & 31; bk = t2 >> 5;
    W = w2; WT = WT2;
  }
  const int tx = threadIdx.x, ty = threadIdx.y;  // 32 x 8
#pragma unroll
  for (int i = 0; i < 32; i += 8)
    tile[ty + i][tx] = W[(size_t)(bk * 32 + ty + i) * N + bn * 32 + tx];
  __syncthreads();
#pragma unroll
  for (int i = 0; i < 32; i += 8)
    WT[(size_t)(bn * 32 + ty + i) * K + bk * 32 + tx] = f2bf(tile[tx][ty + i]);
}

// ---------------- LayerNorm (ddof=1) f32 in -> bf16 out ---------------------
__global__ __launch_bounds__(256)
void ln_kernel(const float* __restrict__ x, const float* __restrict__ alpha,
               const float* __restrict__ beta, unsigned short* __restrict__ out) {
  const int row = blockIdx.x;
  const int t = threadIdx.x;
  const int w = t >> 6, lane = t & 63;
  const float4 v = ((const float4*)(x + (size_t)row * DM))[t];

  float s = v.x + v.y + v.z + v.w;
#pragma unroll
  for (int off = 32; off; off >>= 1) s += __shfl_xor(s, off, 64);
  __shared__ float red1[4];
  __shared__ float red2[4];
  if (lane == 0) red1[w] = s;
  __syncthreads();
  const float mu = (red1[0] + red1[1] + red1[2] + red1[3]) * (1.f / 1024.f);

  const float dx = v.x - mu, dy = v.y - mu, dz = v.z - mu, dw = v.w - mu;
  float sq = dx * dx + dy * dy + dz * dz + dw * dw;
#pragma unroll
  for (int off = 32; off; off >>= 1) sq += __shfl_xor(sq, off, 64);
  if (lane == 0) red2[w] = sq;
  __syncthreads();
  const float var = (red2[0] + red2[1] + red2[2] + red2[3]) * (1.f / 1023.f);
  const float rstd = rsqrtf(var + 1e-6f);

  const float4 a = ((const float4*)alpha)[t];
  const float4 b = ((const float4*)beta)[t];
  const float o0 = dx * rstd * a.x + b.x;
  const float o1 = dy * rstd * a.y + b.y;
  const float o2 = dz * rstd * a.z + b.z;
  const float o3 = dw * rstd * a.w + b.w;
  uint2 ov;
  ov.x = cvt_pk_bf16(o0, o1);
  ov.y = cvt_pk_bf16(o2, o3);
  *(uint2*)(out + (size_t)row * DM + 4 * t) = ov;
}

// ---------------- shared epilogue (MODE 1 / MODE 2) -------------------------
template <int MODE>
__device__ __forceinline__ void epi_store(int m, int n, float v, int Nout,
                                          unsigned short* __restrict__ obf, float* of,
                                          const float* res,
                                          const float* __restrict__ bias0) {
  if (MODE == 1) {
    v += bias0[n] + res[(size_t)m * Nout + n];
    of[(size_t)m * Nout + n] = v;
  } else {
    v += bias0[n];
    const float gv = 0.5f * v * (1.0f + erf_fast(v * 0.70710678118654752f));
    obf[(size_t)m * Nout + n] = f2bf(gv);
  }
}

// ---- XCD supertile mapping for WIDE-N grids (gemms): gridDim.y == 64 -------
__device__ __forceinline__ void supertile_map(int& m0, int& n0) {
  const int L = blockIdx.y * gridDim.x + blockIdx.x;
  const int nwg = gridDim.x * gridDim.y;
  const int chunk = nwg >> 3;
  const int ncols = chunk >> 6;
  const int denom = ncols << 3;
  const int xcd = L & 7, li = L >> 3;
  const int sst = li / denom, wst = li % denom;
  const int by = sst * 8 + (wst & 7);
  const int bx = xcd * ncols + (wst >> 3);
  m0 = by * 128; n0 = bx * 128;
}

// ---------------- 128x128x64 GEMM, DOUBLE-buffered (r8) ---------------------
// For tall-skinny grids 8x64 (O-proj, MLP2). 64KB LDS, 2 blocks/CU.
// M-sliced XCD map: each XCD owns 8 contiguous block-rows x all 8 N-cols.
template <int MODE>
__global__ __launch_bounds__(256, 2)
void gemmk(const unsigned short* __restrict__ A, const unsigned short* __restrict__ B,
           int K, int Nout,
           unsigned short* __restrict__ obf, float* of, const float* res,
           const float* __restrict__ bias0, const float* __restrict__ bias1,
           const float* __restrict__ bias2) {
  __shared__ __attribute__((aligned(16))) unsigned short sA[2][128 * 64];
  __shared__ __attribute__((aligned(16))) unsigned short sB[2][128 * 64];
  const int t = threadIdx.x;
  const int lane = t & 63, wid = t >> 6;
  const int g = lane >> 4, r = lane & 15;
  const int wm = wid >> 1, wn = wid & 1;

  // M-sliced XCD map (requires gridDim.x == 8, gridDim.y == 64)
  const int L = blockIdx.y * gridDim.x + blockIdx.x;
  const int xcd = L & 7, li = L >> 3;
  const int bx = li & 7;
  const int by = xcd * 8 + (li >> 3);
  const int m0 = by * 128, n0 = bx * 128;

  const unsigned short* Ab = A + (size_t)m0 * K;
  const unsigned short* Bb = B + (size_t)n0 * K;

  const int rb = r & 7;
  const int slot0 = (g ^ rb) * 16;
  const int slot1 = ((4 + g) ^ rb) * 16;

  f32x4 acc[4][4];
#pragma unroll
  for (int i2 = 0; i2 < 4; ++i2)
#pragma unroll
    for (int j = 0; j < 4; ++j) acc[i2][j] = (f32x4){0.f, 0.f, 0.f, 0.f};

  auto stage = [&](int buf, int kt) {
#pragma unroll
    for (int s2 = 0; s2 < 4; ++s2) {
      const int f = s2 * 256 + t;
      const int row = f >> 3, c = f & 7;
      const int u = c ^ (row & 7);
      gload16(Ab + (size_t)row * K + kt * 64 + u * 8, &sA[buf][(size_t)row * 64 + c * 8]);
      gload16(Bb + (size_t)row * K + kt * 64 + u * 8, &sB[buf][(size_t)row * 64 + c * 8]);
    }
  };

  const int NT = K >> 6;
  stage(0, 0);
  stage(1, (NT > 1) ? 1 : 0);
  VMCNT8();
  BAR();

  for (int tt = 0; tt < NT; ++tt) {
    const int cur = tt & 1;
    const char* sAc = (const char*)&sA[cur][0];
    const char* sBc = (const char*)&sB[cur][0];

    s16x8 av[4][2], bv[4][2];
#pragma unroll
    for (int i2 = 0; i2 < 4; ++i2) {
      const int rbyte = (wm * 64 + i2 * 16 + r) * 128;
      av[i2][0] = *(const s16x8*)(sAc + rbyte + slot0);
      av[i2][1] = *(const s16x8*)(sAc + rbyte + slot1);
    }
#pragma unroll
    for (int n = 0; n < 4; ++n) {
      const int rbyte = (wn * 64 + n * 16 + r) * 128;
      bv[n][0] = *(const s16x8*)(sBc + rbyte + slot0);
      bv[n][1] = *(const s16x8*)(sBc + rbyte + slot1);
    }
#pragma unroll
    for (int i2 = 0; i2 < 4; ++i2)
#pragma unroll
      for (int n = 0; n < 4; ++n) {
        acc[i2][n] = MFMA16(av[i2][0], bv[n][0], acc[i2][n], 0, 0, 0);
        acc[i2][n] = MFMA16(av[i2][1], bv[n][1], acc[i2][n], 0, 0, 0);
      }

    BAR();
    const int tp2 = (tt + 2 < NT) ? tt + 2 : NT - 1;
    stage(cur, tp2);
    VMCNT8();
    BAR();
  }

  VMCNT0();

#pragma unroll
  for (int i2 = 0; i2 < 4; ++i2)
#pragma unroll
    for (int j = 0; j < 4; ++j) {
      const int m = m0 + wm * 64 + i2 * 16 + 4 * g + j;
#pragma unroll
      for (int nf = 0; nf < 4; ++nf) {
        const int n = n0 + wn * 64 + nf * 16 + r;
        epi_store<MODE>(m, n, acc[i2][nf][j], Nout, obf, of, res, bias0);
      }
    }
}

// ---------------- 128x128x64 GEMM, SINGLE-buffered, 4 blocks/CU -------------
// 32KB LDS; TLP (3 partner blocks) covers the per-tile vmcnt(0) latency.
template <int MODE>
__global__ __launch_bounds__(256, 4)
void gemms(const unsigned short* __restrict__ A, const unsigned short* __restrict__ B,
           int K, int Nout,
           unsigned short* __restrict__ obf, float* of, const float* res,
           const float* __restrict__ bias0, const float* __restrict__ bias1,
           const float* __restrict__ bias2) {
  __shared__ __attribute__((aligned(16))) unsigned short sM[2][128 * 64]; // [0]=A [1]=B
  const int t = threadIdx.x;
  const int lane = t & 63, wid = t >> 6;
  const int g = lane >> 4, r = lane & 15;
  const int wm = wid >> 1, wn = wid & 1;

  int m0, n0;
  supertile_map(m0, n0);

  const unsigned short* Ab = A + (size_t)m0 * K;
  const unsigned short* Bb = B + (size_t)n0 * K;

  const int rb = r & 7;
  const int slot0 = (g ^ rb) * 16;
  const int slot1 = ((4 + g) ^ rb) * 16;

  f32x4 acc[4][4];
#pragma unroll
  for (int i2 = 0; i2 < 4; ++i2)
#pragma unroll
    for (int j = 0; j < 4; ++j) acc[i2][j] = (f32x4){0.f, 0.f, 0.f, 0.f};

  auto stage = [&](int kt) {
#pragma unroll
    for (int s2 = 0; s2 < 4; ++s2) {
      const int f = s2 * 256 + t;
      const int row = f >> 3, c = f & 7;
      const int u = c ^ (row & 7);
      gload16(Ab + (size_t)row * K + kt * 64 + u * 8, &sM[0][(size_t)row * 64 + c * 8]);
      gload16(Bb + (size_t)row * K + kt * 64 + u * 8, &sM[1][(size_t)row * 64 + c * 8]);
    }
  };

  const int NT = K >> 6;
  stage(0);
  VMCNT0();
  BAR();

  for (int tt = 0; tt < NT; ++tt) {
    const char* sAc = (const char*)&sM[0][0];
    const char* sBc = (const char*)&sM[1][0];

    s16x8 av[4][2], bv[4][2];
#pragma unroll
    for (int i2 = 0; i2 < 4; ++i2) {
      const int rbyte = (wm * 64 + i2 * 16 + r) * 128;
      av[i2][0] = *(const s16x8*)(sAc + rbyte + slot0);
      av[i2][1] = *(const s16x8*)(sAc + rbyte + slot1);
    }
#pragma unroll
    for (int n = 0; n < 4; ++n) {
      const int rbyte = (wn * 64 + n * 16 + r) * 128;
      bv[n][0] = *(const s16x8*)(sBc + rbyte + slot0);
      bv[n][1] = *(const s16x8*)(sBc + rbyte + slot1);
    }
#pragma unroll
    for (int i2 = 0; i2 < 4; ++i2)
#pragma unroll
      for (int n = 0; n < 4; ++n) {
        acc[i2][n] = MFMA16(av[i2][0], bv[n][0], acc[i2][n], 0, 0, 0);
        acc[i2][n] = MFMA16(av[i2][1], bv[n][1], acc[i2][n], 0, 0, 0);
      }

    BAR();                                    // all waves done reading sM
    stage((tt + 1 < NT) ? tt + 1 : tt);       // unconditional clamped re-stage
    VMCNT0();                                 // own DMAs landed
    BAR();                                    // all waves' DMAs landed
  }

  if (MODE == 0) {
    const int which = n0 >> 10;
    const int hn = ((n0 & 1023) + wn * 64) >> 6;
    const int mwave = m0 + wm * 64;
    const int b = mwave >> 10, s_wb = mwave & 1023;
    if (which == 2) {
      // V: transpose 64x64 wave-tile in this wave's 8KB LDS slice
      unsigned short* tl = (unsigned short*)&sM[0][0] + (size_t)wid * (64 * 64);
#pragma unroll
      for (int i2 = 0; i2 < 4; ++i2)
#pragma unroll
        for (int nf = 0; nf < 4; ++nf) {
          const int d = nf * 16 + r;
          const float bias = bias2[hn * 64 + d];
          s16x4 o;
#pragma unroll
          for (int j = 0; j < 4; ++j) o[j] = (short)f2bf(acc[i2][nf][j] + bias);
          *(s16x4*)&tl[d * 64 + i2 * 16 + 4 * g] = o;
        }
      unsigned short* vout = obf + (size_t)2 * (M_TOTAL * DM) +
                             ((size_t)(b * NH + hn) * DH) * SEQ + s_wb;
#pragma unroll
      for (int p2 = 0; p2 < 16; ++p2) {
        const int d = p2 * 4 + g;
        const s16x4 v = *(const s16x4*)&tl[d * 64 + 4 * r];
        *(s16x4*)(vout + (size_t)d * SEQ + 4 * r) = v;
      }
    } else {
#pragma unroll
      for (int i2 = 0; i2 < 4; ++i2)
#pragma unroll
        for (int nf = 0; nf < 4; ++nf) {
          const int d = nf * 16 + r;
          const float bias = (which == 0) ? bias0[hn * 64 + d] : bias1[hn * 64 + d];
          const int s_base = s_wb + i2 * 16 + 4 * g;
#pragma unroll
          for (int j = 0; j < 4; ++j) {
            float v = acc[i2][nf][j] + bias;
            if (which == 0) v *= 0.1803368801f;  // 1/8 * log2(e): exp2-domain scores
            obf[(size_t)which * (M_TOTAL * DM) +
                (((size_t)(b * NH + hn) * SEQ + (s_base + j)) * DH + d)] = f2bf(v);
          }
        }
    }
  } else {
#pragma unroll
    for (int i2 = 0; i2 < 4; ++i2)
#pragma unroll
      for (int j = 0; j < 4; ++j) {
        const int m = m0 + wm * 64 + i2 * 16 + 4 * g + j;
#pragma unroll
        for (int nf = 0; nf < 4; ++nf) {
          const int n = n0 + wn * 64 + nf * 16 + r;
          epi_store<MODE>(m, n, acc[i2][nf][j], Nout, obf, of, res, bias0);
        }
      }
  }
}

// ---------------- flash attention: QBLK=128, 8 waves, head-affinity swizzle -
// Q pre-scaled by (1/8)*log2(e) -> softmax in exp2 domain.
// V already transposed: VT[bh][d][s] at QKV slice 2.
// All 8 q-blocks of a head land on one XCD (block L -> XCD L&7) so its
// 256KB K/V stays L2-resident.
__global__ __launch_bounds__(512)
void attn_kernel(const unsigned short* __restrict__ QKV,
                 unsigned short* __restrict__ O) {
  const unsigned short* Qg = QKV;
  const unsigned short* Kg = QKV + (size_t)M_TOTAL * DM;
  const unsigned short* VTg = QKV + 2 * (size_t)M_TOTAL * DM;
  const int L = blockIdx.y * gridDim.x + blockIdx.x;   // grid (8,128) -> 1024
  const int bh = 8 * ((L >> 3) & 15) + (L & 7);        // head-affinity: XCD = L&7
  const int q0 = ((L >> 3) >> 4) * 128;
  const int t = threadIdx.x, w = t >> 6, lane = t & 63;
  const int g = lane >> 4, r = lane & 15;
  const unsigned short* Qb = Qg + (size_t)bh * SEQ * DH;
  const unsigned short* Kb = Kg + (size_t)bh * SEQ * DH;
  const unsigned short* VTb = VTg + (size_t)bh * DH * SEQ;

  __shared__ __attribute__((aligned(16))) unsigned short sK[2][64 * 64];
  __shared__ __attribute__((aligned(16))) unsigned short sV[2][64 * 64];

  s16x8 qf[2];
  {
    const unsigned short* qrow = Qb + (size_t)(q0 + w * 16 + r) * DH;
    qf[0] = *(const s16x8*)(qrow + g * 8);
    qf[1] = *(const s16x8*)(qrow + 32 + g * 8);
  }

  f32x4 oacc[4];
#pragma unroll
  for (int i = 0; i < 4; ++i) oacc[i] = (f32x4){0.f, 0.f, 0.f, 0.f};
  float mrun = -1e30f, lrun = 0.f;

  // 512 threads: one pass stages the full 64x64 K and V tiles (512+512 gloads)
  auto stage = [&](int buf, int kt) {
    const int f = t;                          // 0..511: row = f>>3, chunk = f&7
    const int row = f >> 3, u = (f & 7) ^ (row & 7);
    gload16(Kb + (size_t)(kt * 64 + row) * DH + u * 8, &sK[buf][f * 8]);
    gload16(VTb + (size_t)row * SEQ + kt * 64 + u * 8, &sV[buf][f * 8]);
  };

  stage(0, 0);
  __syncthreads();

  for (int kt = 0; kt < SEQ / 64; ++kt) {
    const int cur = kt & 1;
    if (kt < SEQ / 64 - 1) stage(cur ^ 1, kt + 1);

    f32x4 sc[4];
#pragma unroll
    for (int nf = 0; nf < 4; ++nf) {
      sc[nf] = (f32x4){0.f, 0.f, 0.f, 0.f};
      const int rowk = nf * 16 + r;
#pragma unroll
      for (int ks = 0; ks < 2; ++ks) {
        const int u = (4 * ks + g) ^ (rowk & 7);
        const s16x8 kf = *(const s16x8*)&sK[cur][rowk * 64 + u * 8];
        sc[nf] = __builtin_amdgcn_mfma_f32_16x16x32_bf16(kf, qf[ks], sc[nf], 0, 0, 0);
      }
    }

    float pm = -1e30f;
#pragma unroll
    for (int nf = 0; nf < 4; ++nf)
#pragma unroll
      for (int j = 0; j < 4; ++j) pm = fmaxf(pm, sc[nf][j]);
    pm = fmaxf(pm, __shfl_xor(pm, 16, 64));
    pm = fmaxf(pm, __shfl_xor(pm, 32, 64));

    if (!__all(pm - mrun <= 8.0f)) {
      const float mnew = fmaxf(mrun, pm);
      const float alpha = exp2_fast(mrun - mnew);
      mrun = mnew;
      lrun *= alpha;
      float ao[4];
#pragma unroll
      for (int j = 0; j < 4; ++j) ao[j] = __shfl(alpha, 4 * g + j, 64);
#pragma unroll
      for (int nf2 = 0; nf2 < 4; ++nf2)
#pragma unroll
        for (int j = 0; j < 4; ++j) oacc[nf2][j] *= ao[j];
    }

    float p[4][4];
    float ps = 0.f;
#pragma unroll
    for (int nf = 0; nf < 4; ++nf)
#pragma unroll
      for (int j = 0; j < 4; ++j) {
        p[nf][j] = exp2_fast(sc[nf][j] - mrun);   // bounded by 2^8
        ps += p[nf][j];
      }
    ps += __shfl_xor(ps, 16, 64);
    ps += __shfl_xor(ps, 32, 64);
    lrun += ps;

    unsigned int pk[4][2];
#pragma unroll
    for (int nf = 0; nf < 4; ++nf)
#pragma unroll
      for (int jp = 0; jp < 2; ++jp)
        pk[nf][jp] = cvt_pk_bf16(p[nf][2 * jp], p[nf][2 * jp + 1]);

    unsigned int pa32[2][4];
#pragma unroll
    for (int ks = 0; ks < 2; ++ks)
#pragma unroll
      for (int q2 = 0; q2 < 4; ++q2) {
        const int src = r + 32 * (g & 1) + 16 * (q2 >> 1);
        const unsigned int a = (unsigned int)__shfl((int)pk[2 * ks][q2 & 1], src, 64);
        const unsigned int b = (unsigned int)__shfl((int)pk[2 * ks + 1][q2 & 1], src, 64);
        pa32[ks][q2] = (g >> 1) ? b : a;
      }
    s16x8 pa[2];
#pragma unroll
    for (int ks = 0; ks < 2; ++ks) {
      u32x4 pw;
      pw[0] = pa32[ks][0]; pw[1] = pa32[ks][1];
      pw[2] = pa32[ks][2]; pw[3] = pa32[ks][3];
      pa[ks] = __builtin_bit_cast(s16x8, pw);
    }

#pragma unroll
    for (int nf2 = 0; nf2 < 4; ++nf2) {
      const int rowd = nf2 * 16 + r;
#pragma unroll
      for (int ks = 0; ks < 2; ++ks) {
        const int u = (4 * ks + g) ^ (rowd & 7);
        const s16x8 vb = *(const s16x8*)&sV[cur][rowd * 64 + u * 8];
        oacc[nf2] = __builtin_amdgcn_mfma_f32_16x16x32_bf16(pa[ks], vb, oacc[nf2], 0, 0, 0);
      }
    }
    __syncthreads();
  }

  const int b = bh >> 4, h = bh & 15;
  const float linv = 1.f / lrun;
#pragma unroll
  for (int j = 0; j < 4; ++j) {
    const float lo = __shfl(linv, 4 * g + j, 64);
    const int q = q0 + w * 16 + 4 * g + j;
    const size_t orow = ((size_t)(b * SEQ + q)) * DM + h * DH;
#pragma unroll
    for (int nf2 = 0; nf2 < 4; ++nf2)
      O[orow + nf2 * 16 + r] = f2bf(oacc[nf2][j] * lo);
  }
}

// ---------------------------------------------------------------------------
extern "C" void kernel_launch(void* const* d_in, const int* in_sizes, int n_in,
                              void* d_out, int out_size, void* d_ws, size_t ws_size,
                              hipStream_t stream) {
  const float* x   = (const float*)d_in[0];
  const float* al1 = (const float*)d_in[1];
  const float* be1 = (const float*)d_in[2];
  const float* al2 = (const float*)d_in[3];
  const float* be2 = (const float*)d_in[4];
  const float* wq  = (const float*)d_in[5];
  const float* bq  = (const float*)d_in[6];
  const float* wk  = (const float*)d_in[7];
  const float* bk  = (const float*)d_in[8];
  const float* wv  = (const float*)d_in[9];
  const float* bv  = (const float*)d_in[10];
  const float* wo  = (const float*)d_in[11];
  const float* bo  = (const float*)d_in[12];
  const float* w1  = (const float*)d_in[13];
  const float* b1  = (const float*)d_in[14];
  const float* w2  = (const float*)d_in[15];
  const float* b2  = (const float*)d_in[16];
  float* dout = (float*)d_out;

  unsigned short* ws = (unsigned short*)d_ws;
  size_t off = 0;
  auto alloc = [&](size_t n) { unsigned short* p = ws + off; off += n; return p; };
  unsigned short* WTqkv = alloc((size_t)3072 * 1024);
  unsigned short* WTo   = alloc((size_t)1024 * 1024);
  unsigned short* WT1   = alloc((size_t)4096 * 1024);
  unsigned short* WT2   = alloc((size_t)1024 * 4096);
  unsigned short* xn    = alloc((size_t)M_TOTAL * DM);
  unsigned short* QKVb  = alloc((size_t)3 * M_TOTAL * DM);  // Q, K, V^T slices
  unsigned short* attn  = alloc((size_t)M_TOTAL * DM);
  unsigned short* h1    = alloc((size_t)M_TOTAL * HID);
  (void)ws_size; (void)in_sizes; (void)n_in; (void)out_size;

  // all 6 weight transposes in one launch
  tcast_all<<<12288, dim3(32, 8), 0, stream>>>(wq, wk, wv, wo, w1, w2,
                                               WTqkv, WTo, WT1, WT2);

  // LN1: x -> xn (bf16)
  ln_kernel<<<M_TOTAL, 256, 0, stream>>>(x, al1, be1, xn);
  // QKV projection: 1536 wgs -> single-buffered 4-blocks/CU kernel
  gemms<0><<<dim3(24, 64), 256, 0, stream>>>(xn, WTqkv, 1024, 3072,
                                             QKVb, nullptr, nullptr, bq, bk, bv);
  // attention: QBLK=128, 8 waves, head-affinity XCD swizzle
  attn_kernel<<<dim3(8, 128), 512, 0, stream>>>(QKVb, attn);
  // O projection + residual: 512 wgs -> double-buffered kernel (M-sliced map)
  gemmk<1><<<dim3(8, 64), 256, 0, stream>>>(attn, WTo, 1024, 1024,
                                            nullptr, dout, x, bo, nullptr, nullptr);
  // LN2: dout -> xn (bf16)
  ln_kernel<<<M_TOTAL, 256, 0, stream>>>(dout, al2, be2, xn);
  // MLP1 + GELU: 2048 wgs -> single-buffered 4-blocks/CU kernel
  gemms<2><<<dim3(32, 64), 256, 0, stream>>>(xn, WT1, 1024, 4096,
                                             h1, nullptr, nullptr, b1, nullptr, nullptr);
  // MLP2 + residual: 512 wgs -> double-buffered kernel (M-sliced map)
  gemmk<1><<<dim3(8, 64), 256, 0, stream>>>(h1, WT2, 4096, 1024,
                                            nullptr, dout, dout, b2, nullptr, nullptr);
}